// Round 1
// baseline (2215.411 us; speedup 1.0000x reference)
//
#include <hip/hip_runtime.h>
#include <hip/hip_bf16.h>

#define NN 50000
#define EE 800000
#define FF 256
#define HH 256
#define CC 10
#define BB 128
#define VV 4
#define SS 16   // pooling strips per batch

// ---------------- x0 = x * dropout_mask ----------------
__global__ __launch_bounds__(256) void k_mul(const float4* __restrict__ x,
                                             const float4* __restrict__ dm,
                                             float4* __restrict__ x0, int n4) {
  int i = blockIdx.x * 256 + threadIdx.x;
  if (i < n4) {
    float4 a = x[i], b = dm[i];
    x0[i] = make_float4(a.x * b.x, a.y * b.y, a.z * b.z, a.w * b.w);
  }
}

// ---------------- degree count (by row) ----------------
__global__ __launch_bounds__(256) void k_deg(const int* __restrict__ row, int* __restrict__ deg) {
  int i = blockIdx.x * 256 + threadIdx.x;
  if (i < EE) atomicAdd(&deg[row[i]], 1);
}

// ---------------- exclusive scan -> row_ptr ----------------
__global__ __launch_bounds__(256) void k_scan(const int* __restrict__ deg, int* __restrict__ rptr) {
  __shared__ int sums[256];
  int tid = threadIdx.x;
  const int chunk = (NN + 255) / 256;
  int st = tid * chunk;
  int en = st + chunk; if (en > NN) en = NN;
  int s = 0;
  for (int i = st; i < en; ++i) s += deg[i];
  sums[tid] = s;
  __syncthreads();
  if (tid == 0) {
    int run = 0;
    for (int i = 0; i < 256; ++i) { int t = sums[i]; sums[i] = run; run += t; }
  }
  __syncthreads();
  int run = sums[tid];
  for (int i = st; i < en; ++i) { rptr[i] = run; run += deg[i]; }
  if (tid == 255) rptr[NN] = run;
}

// ---------------- scatter edges into CSR ----------------
__global__ __launch_bounds__(256) void k_scatter(const int* __restrict__ row,
                                                 const int* __restrict__ col,
                                                 const int* __restrict__ rptr,
                                                 int* __restrict__ fill,
                                                 int* __restrict__ csort) {
  int i = blockIdx.x * 256 + threadIdx.x;
  if (i < EE) {
    int r = row[i];
    int p = rptr[r] + atomicAdd(&fill[r], 1);
    csort[p] = col[i];
  }
}

// ---------------- batch_ptr via binary search (batch sorted) ----------------
__global__ __launch_bounds__(256) void k_bptr(const int* __restrict__ batch, int* __restrict__ bptr) {
  int b = threadIdx.x;
  if (b > BB) return;
  int lo = 0, hi = NN;
  while (lo < hi) { int mid = (lo + hi) >> 1; if (batch[mid] < b) lo = mid + 1; else hi = mid; }
  bptr[b] = lo;
}

// ---------------- propagation: out[r] = (in[r](*m) + sum in[c](*m)) / (deg+1) ----------------
template <bool MASKED>
__global__ __launch_bounds__(256) void k_prop(const float* __restrict__ in,
                                              float* __restrict__ out,
                                              const int* __restrict__ rptr,
                                              const int* __restrict__ csort,
                                              const float* __restrict__ mask) {
  int node = blockIdx.x * 4 + (threadIdx.x >> 6);
  if (node >= NN) return;
  int lane = threadIdx.x & 63;
  const float4* in4 = reinterpret_cast<const float4*>(in);
  int s = rptr[node], e = rptr[node + 1];
  float4 acc;
  {
    float4 v = in4[(size_t)node * 64 + lane];
    float m = MASKED ? mask[node] : 1.0f;
    acc = make_float4(v.x * m, v.y * m, v.z * m, v.w * m);
  }
  int j = s;
  for (; j + 1 < e; j += 2) {
    int c0 = csort[j], c1 = csort[j + 1];
    float m0 = MASKED ? mask[c0] : 1.0f;
    float m1 = MASKED ? mask[c1] : 1.0f;
    float4 v0 = in4[(size_t)c0 * 64 + lane];
    float4 v1 = in4[(size_t)c1 * 64 + lane];
    acc.x += v0.x * m0 + v1.x * m1;
    acc.y += v0.y * m0 + v1.y * m1;
    acc.z += v0.z * m0 + v1.z * m1;
    acc.w += v0.w * m0 + v1.w * m1;
  }
  if (j < e) {
    int c0 = csort[j];
    float m0 = MASKED ? mask[c0] : 1.0f;
    float4 v0 = in4[(size_t)c0 * 64 + lane];
    acc.x += v0.x * m0; acc.y += v0.y * m0; acc.z += v0.z * m0; acc.w += v0.w * m0;
  }
  float sc = 1.0f / (float)(e - s + 1);
  reinterpret_cast<float4*>(out)[(size_t)node * 64 + lane] =
      make_float4(acc.x * sc, acc.y * sc, acc.z * sc, acc.w * sc);
}

// ---------------- Z = relu(A @ W1 + b1), 64x64 tile ----------------
__global__ __launch_bounds__(256) void k_gemm(const float* __restrict__ A,
                                              const float* __restrict__ W,
                                              const float* __restrict__ bias,
                                              float* __restrict__ Z) {
  __shared__ float As[64][33];
  __shared__ float Ws[32][64];
  int tid = threadIdx.x;
  int row0 = blockIdx.x * 64;
  int col0 = blockIdx.y * 64;
  int ty = tid >> 4, tx = tid & 15;
  int arow = tid >> 2, acol = (tid & 3) * 8;
  int wrow = tid >> 3, wcol = (tid & 7) * 8;
  float acc[4][4] = {};
  for (int kk = 0; kk < FF; kk += 32) {
    float4 a0, a1;
    int gr = row0 + arow;
    if (gr < NN) {
      const float* ap = A + (size_t)gr * FF + kk + acol;
      a0 = *reinterpret_cast<const float4*>(ap);
      a1 = *reinterpret_cast<const float4*>(ap + 4);
    } else {
      a0 = make_float4(0.f, 0.f, 0.f, 0.f); a1 = a0;
    }
    As[arow][acol + 0] = a0.x; As[arow][acol + 1] = a0.y;
    As[arow][acol + 2] = a0.z; As[arow][acol + 3] = a0.w;
    As[arow][acol + 4] = a1.x; As[arow][acol + 5] = a1.y;
    As[arow][acol + 6] = a1.z; As[arow][acol + 7] = a1.w;
    const float* wp = W + (size_t)(kk + wrow) * HH + col0 + wcol;
    *reinterpret_cast<float4*>(&Ws[wrow][wcol]) = *reinterpret_cast<const float4*>(wp);
    *reinterpret_cast<float4*>(&Ws[wrow][wcol + 4]) = *reinterpret_cast<const float4*>(wp + 4);
    __syncthreads();
#pragma unroll
    for (int k = 0; k < 32; ++k) {
      float av[4], wv[4];
#pragma unroll
      for (int i = 0; i < 4; ++i) av[i] = As[ty * 4 + i][k];
#pragma unroll
      for (int j = 0; j < 4; ++j) wv[j] = Ws[k][tx * 4 + j];
#pragma unroll
      for (int i = 0; i < 4; ++i)
#pragma unroll
        for (int j = 0; j < 4; ++j) acc[i][j] += av[i] * wv[j];
    }
    __syncthreads();
  }
  float4 bs = *reinterpret_cast<const float4*>(&bias[col0 + tx * 4]);
#pragma unroll
  for (int i = 0; i < 4; ++i) {
    int r = row0 + ty * 4 + i;
    if (r < NN) {
      float4 o = make_float4(fmaxf(acc[i][0] + bs.x, 0.f), fmaxf(acc[i][1] + bs.y, 0.f),
                             fmaxf(acc[i][2] + bs.z, 0.f), fmaxf(acc[i][3] + bs.w, 0.f));
      *reinterpret_cast<float4*>(&Z[(size_t)r * HH + col0 + tx * 4]) = o;
    }
  }
}

// ---------------- strip-parallel pooled partial sums (no atomics) ----------------
__global__ __launch_bounds__(256) void k_pool(const float* __restrict__ z,
                                              const int* __restrict__ bptr,
                                              float* __restrict__ part) {
  int b = blockIdx.x, s = blockIdx.y, col = threadIdx.x;
  int st = bptr[b], en = bptr[b + 1];
  int cnt = en - st;
  int per = (cnt + SS - 1) / SS;
  int rs = st + s * per;
  int re = rs + per; if (re > en) re = en;
  float acc = 0.f;
  for (int r = rs; r < re; ++r) acc += z[(size_t)r * HH + col];
  part[((size_t)s * BB + b) * HH + col] = acc;
}

// ---------------- head: meanpool -> @W2+b2 -> @Wc+bc -> softmax ----------------
__global__ __launch_bounds__(256) void k_head(const float* __restrict__ part,
                                              const int* __restrict__ bptr,
                                              const float* __restrict__ W2,
                                              const float* __restrict__ b2,
                                              const float* __restrict__ Wc,
                                              const float* __restrict__ bc,
                                              float* __restrict__ probs,
                                              float* __restrict__ logits) {
  int v = blockIdx.x / BB;
  int b = blockIdx.x % BB;
  int h = threadIdx.x;
  __shared__ float mr[HH];
  __shared__ float vr[HH];
  __shared__ float scs[CC];
  float acc = 0.f;
  for (int s = 0; s < SS; ++s)
    acc += part[(((size_t)v * SS + s) * BB + b) * HH + h];
  int cnt = bptr[b + 1] - bptr[b]; if (cnt < 1) cnt = 1;
  mr[h] = acc / (float)cnt;
  __syncthreads();
  float a = b2[h];
  for (int k = 0; k < HH; ++k) a += mr[k] * W2[k * HH + h];
  vr[h] = a;
  __syncthreads();
  if (h < CC) {
    float t = bc[h];
    for (int k = 0; k < HH; ++k) t += vr[k] * Wc[k * CC + h];
    scs[h] = t;
  }
  __syncthreads();
  if (h < CC) {
    float m = scs[0];
    for (int c = 1; c < CC; ++c) m = fmaxf(m, scs[c]);
    float den = 0.f;
    for (int c = 0; c < CC; ++c) den += expf(scs[c] - m);
    float p = expf(scs[h] - m) / den;
    probs[((size_t)v * BB + b) * CC + h] = p;
    if (v == 0) logits[b * CC + h] = scs[h];
  }
}

// ---------------- loss: consistency + entropy ----------------
__global__ __launch_bounds__(256) void k_loss(const float* __restrict__ probs, float* __restrict__ out) {
  __shared__ float mp[BB * CC];
  __shared__ float red[8];
  int tid = threadIdx.x;
  float ent = 0.f;
  for (int i = tid; i < BB * CC; i += 256) {
    float m = 0.25f * (probs[i] + probs[BB * CC + i] + probs[2 * BB * CC + i] + probs[3 * BB * CC + i]);
    mp[i] = m;
    ent += m * logf(m + 1e-8f);
  }
  __syncthreads();
  float cons = 0.f;
  for (int i = tid; i < VV * BB * CC; i += 256) {
    float d = probs[i] - mp[i % (BB * CC)];
    cons += d * d;
  }
  for (int o = 32; o > 0; o >>= 1) {
    cons += __shfl_down(cons, o, 64);
    ent += __shfl_down(ent, o, 64);
  }
  int wid = tid >> 6, lane = tid & 63;
  if (lane == 0) { red[wid] = cons; red[4 + wid] = ent; }
  __syncthreads();
  if (tid == 0) {
    float c = red[0] + red[1] + red[2] + red[3];
    float e2 = red[4] + red[5] + red[6] + red[7];
    out[0] = c / (float)(VV * BB) - e2 / (float)BB;
  }
}

extern "C" void kernel_launch(void* const* d_in, const int* in_sizes, int n_in,
                              void* d_out, int out_size, void* d_ws, size_t ws_size,
                              hipStream_t stream) {
  const float* x     = (const float*)d_in[0];
  const int*   erow  = (const int*)d_in[1];          // edge_index[0]
  const int*   ecol  = ((const int*)d_in[1]) + EE;   // edge_index[1]
  const int*   batch = (const int*)d_in[2];
  const float* dm    = (const float*)d_in[3];
  const float* nmask = (const float*)d_in[4];
  const float* W1    = (const float*)d_in[5];
  const float* b1    = (const float*)d_in[6];
  const float* W2    = (const float*)d_in[7];
  const float* b2    = (const float*)d_in[8];
  const float* Wc    = (const float*)d_in[9];
  const float* bc    = (const float*)d_in[10];
  float* out = (float*)d_out;

  char* ws = (char*)d_ws;
  size_t off = 0;
  auto carve = [&](size_t bytes) -> char* {
    char* p = ws + off;
    off = (off + bytes + 255) & ~(size_t)255;
    return p;
  };
  float* x0    = (float*)carve((size_t)NN * FF * 4);
  float* buf0  = (float*)carve((size_t)NN * FF * 4);
  float* buf1  = (float*)carve((size_t)NN * FF * 4);
  float* part  = (float*)carve((size_t)VV * SS * BB * HH * 4);
  int*   deg   = (int*)carve((size_t)NN * 4);
  int*   fill  = (int*)carve((size_t)NN * 4);
  int*   rptr  = (int*)carve((size_t)(NN + 1) * 4);
  int*   csort = (int*)carve((size_t)EE * 4);
  int*   bptr  = (int*)carve((size_t)(BB + 1) * 4);
  float* probs = (float*)carve((size_t)VV * BB * CC * 4);

  hipMemsetAsync(deg, 0, (size_t)NN * 4, stream);
  hipMemsetAsync(fill, 0, (size_t)NN * 4, stream);

  k_mul<<<(NN * FF / 4 + 255) / 256, 256, 0, stream>>>(
      (const float4*)x, (const float4*)dm, (float4*)x0, NN * FF / 4);
  k_deg<<<(EE + 255) / 256, 256, 0, stream>>>(erow, deg);
  k_scan<<<1, 256, 0, stream>>>(deg, rptr);
  k_scatter<<<(EE + 255) / 256, 256, 0, stream>>>(erow, ecol, rptr, fill, csort);
  k_bptr<<<1, 256, 0, stream>>>(batch, bptr);

  for (int v = 0; v < VV; ++v) {
    const float* mask = nmask + (size_t)v * NN;
    k_prop<true><<<(NN + 3) / 4, 256, 0, stream>>>(x0, buf0, rptr, csort, mask);
    k_prop<false><<<(NN + 3) / 4, 256, 0, stream>>>(buf0, buf1, rptr, csort, nullptr);
    k_prop<false><<<(NN + 3) / 4, 256, 0, stream>>>(buf1, buf0, rptr, csort, nullptr);
    k_gemm<<<dim3((NN + 63) / 64, HH / 64), 256, 0, stream>>>(buf0, W1, b1, buf1);
    k_pool<<<dim3(BB, SS), 256, 0, stream>>>(buf1, bptr, part + (size_t)v * SS * BB * HH);
  }
  k_head<<<VV * BB, 256, 0, stream>>>(part, bptr, W2, b2, Wc, bc, probs, out);
  k_loss<<<1, 256, 0, stream>>>(probs, out + BB * CC);
}

// Round 2
// 1579.152 us; speedup vs baseline: 1.4029x; 1.4029x over previous
//
#include <hip/hip_runtime.h>
#include <hip/hip_bf16.h>

#define NN 50000
#define EE 800000
#define FF 256
#define HH 256
#define CC 10
#define BB 128
#define VV 4
#define SS 16   // pooling strips per batch

// ---------------- degree count (by row) ----------------
__global__ __launch_bounds__(256) void k_deg(const int* __restrict__ row, int* __restrict__ deg) {
  int i = blockIdx.x * 256 + threadIdx.x;
  if (i < EE) atomicAdd(&deg[row[i]], 1);
}

// ---------------- exclusive scan -> row_ptr ----------------
__global__ __launch_bounds__(256) void k_scan(const int* __restrict__ deg, int* __restrict__ rptr) {
  __shared__ int sums[256];
  int tid = threadIdx.x;
  const int chunk = (NN + 255) / 256;
  int st = tid * chunk;
  int en = st + chunk; if (en > NN) en = NN;
  int s = 0;
  for (int i = st; i < en; ++i) s += deg[i];
  sums[tid] = s;
  __syncthreads();
  if (tid == 0) {
    int run = 0;
    for (int i = 0; i < 256; ++i) { int t = sums[i]; sums[i] = run; run += t; }
  }
  __syncthreads();
  int run = sums[tid];
  for (int i = st; i < en; ++i) { rptr[i] = run; run += deg[i]; }
  if (tid == 255) rptr[NN] = run;
}

// ---------------- scatter edges into CSR ----------------
__global__ __launch_bounds__(256) void k_scatter(const int* __restrict__ row,
                                                 const int* __restrict__ col,
                                                 const int* __restrict__ rptr,
                                                 int* __restrict__ fill,
                                                 int* __restrict__ csort) {
  int i = blockIdx.x * 256 + threadIdx.x;
  if (i < EE) {
    int r = row[i];
    int p = rptr[r] + atomicAdd(&fill[r], 1);
    csort[p] = col[i];
  }
}

// ---------------- batch_ptr via binary search (batch sorted) ----------------
__global__ __launch_bounds__(256) void k_bptr(const int* __restrict__ batch, int* __restrict__ bptr) {
  int b = threadIdx.x;
  if (b > BB) return;
  int lo = 0, hi = NN;
  while (lo < hi) { int mid = (lo + hi) >> 1; if (batch[mid] < b) lo = mid + 1; else hi = mid; }
  bptr[b] = lo;
}

// ---------------- hop1 merged over 4 views: out_v[r] = (sum_c y[c]*m_v[c] + y[r]*m_v[r]) / (deg+1)
__global__ __launch_bounds__(256) void k_prop1(const float* __restrict__ y,
                                               float* __restrict__ h1,
                                               const int* __restrict__ rptr,
                                               const int* __restrict__ csort,
                                               const float* __restrict__ nmask) {
  int node = blockIdx.x * 4 + (threadIdx.x >> 6);
  if (node >= NN) return;
  int lane = threadIdx.x & 63;
  const float4* in4 = reinterpret_cast<const float4*>(y);
  int s = rptr[node], e = rptr[node + 1];
  float4 a0, a1, a2, a3;
  {
    float4 v = in4[(size_t)node * 64 + lane];
    float m0 = nmask[node], m1 = nmask[NN + node], m2 = nmask[2 * NN + node], m3 = nmask[3 * NN + node];
    a0 = make_float4(v.x * m0, v.y * m0, v.z * m0, v.w * m0);
    a1 = make_float4(v.x * m1, v.y * m1, v.z * m1, v.w * m1);
    a2 = make_float4(v.x * m2, v.y * m2, v.z * m2, v.w * m2);
    a3 = make_float4(v.x * m3, v.y * m3, v.z * m3, v.w * m3);
  }
  int j = s;
  for (; j + 1 < e; j += 2) {
    int c0 = csort[j], c1 = csort[j + 1];
    float4 v0 = in4[(size_t)c0 * 64 + lane];
    float4 v1 = in4[(size_t)c1 * 64 + lane];
    float p0 = nmask[c0], p1 = nmask[NN + c0], p2 = nmask[2 * NN + c0], p3 = nmask[3 * NN + c0];
    float q0 = nmask[c1], q1 = nmask[NN + c1], q2 = nmask[2 * NN + c1], q3 = nmask[3 * NN + c1];
    a0.x += v0.x * p0 + v1.x * q0; a0.y += v0.y * p0 + v1.y * q0;
    a0.z += v0.z * p0 + v1.z * q0; a0.w += v0.w * p0 + v1.w * q0;
    a1.x += v0.x * p1 + v1.x * q1; a1.y += v0.y * p1 + v1.y * q1;
    a1.z += v0.z * p1 + v1.z * q1; a1.w += v0.w * p1 + v1.w * q1;
    a2.x += v0.x * p2 + v1.x * q2; a2.y += v0.y * p2 + v1.y * q2;
    a2.z += v0.z * p2 + v1.z * q2; a2.w += v0.w * p2 + v1.w * q2;
    a3.x += v0.x * p3 + v1.x * q3; a3.y += v0.y * p3 + v1.y * q3;
    a3.z += v0.z * p3 + v1.z * q3; a3.w += v0.w * p3 + v1.w * q3;
  }
  if (j < e) {
    int c0 = csort[j];
    float4 v0 = in4[(size_t)c0 * 64 + lane];
    float p0 = nmask[c0], p1 = nmask[NN + c0], p2 = nmask[2 * NN + c0], p3 = nmask[3 * NN + c0];
    a0.x += v0.x * p0; a0.y += v0.y * p0; a0.z += v0.z * p0; a0.w += v0.w * p0;
    a1.x += v0.x * p1; a1.y += v0.y * p1; a1.z += v0.z * p1; a1.w += v0.w * p1;
    a2.x += v0.x * p2; a2.y += v0.y * p2; a2.z += v0.z * p2; a2.w += v0.w * p2;
    a3.x += v0.x * p3; a3.y += v0.y * p3; a3.z += v0.z * p3; a3.w += v0.w * p3;
  }
  float sc = 1.0f / (float)(e - s + 1);
  float4* o = reinterpret_cast<float4*>(h1);
  size_t base = (size_t)node * 64 + lane;
  o[base] = make_float4(a0.x * sc, a0.y * sc, a0.z * sc, a0.w * sc);
  o[(size_t)NN * 64 + base] = make_float4(a1.x * sc, a1.y * sc, a1.z * sc, a1.w * sc);
  o[(size_t)2 * NN * 64 + base] = make_float4(a2.x * sc, a2.y * sc, a2.z * sc, a2.w * sc);
  o[(size_t)3 * NN * 64 + base] = make_float4(a3.x * sc, a3.y * sc, a3.z * sc, a3.w * sc);
}

// ---------------- propagation: out[r] = (in[r](*m) + sum in[c](*m)) / (deg+1) ----------------
template <bool MASKED>
__global__ __launch_bounds__(256) void k_prop(const float* __restrict__ in,
                                              float* __restrict__ out,
                                              const int* __restrict__ rptr,
                                              const int* __restrict__ csort,
                                              const float* __restrict__ mask) {
  int node = blockIdx.x * 4 + (threadIdx.x >> 6);
  if (node >= NN) return;
  int lane = threadIdx.x & 63;
  const float4* in4 = reinterpret_cast<const float4*>(in);
  int s = rptr[node], e = rptr[node + 1];
  float4 acc;
  {
    float4 v = in4[(size_t)node * 64 + lane];
    float m = MASKED ? mask[node] : 1.0f;
    acc = make_float4(v.x * m, v.y * m, v.z * m, v.w * m);
  }
  int j = s;
  for (; j + 3 < e; j += 4) {
    int c0 = csort[j], c1 = csort[j + 1], c2 = csort[j + 2], c3 = csort[j + 3];
    float m0 = MASKED ? mask[c0] : 1.0f;
    float m1 = MASKED ? mask[c1] : 1.0f;
    float m2 = MASKED ? mask[c2] : 1.0f;
    float m3 = MASKED ? mask[c3] : 1.0f;
    float4 v0 = in4[(size_t)c0 * 64 + lane];
    float4 v1 = in4[(size_t)c1 * 64 + lane];
    float4 v2 = in4[(size_t)c2 * 64 + lane];
    float4 v3 = in4[(size_t)c3 * 64 + lane];
    acc.x += v0.x * m0 + v1.x * m1 + v2.x * m2 + v3.x * m3;
    acc.y += v0.y * m0 + v1.y * m1 + v2.y * m2 + v3.y * m3;
    acc.z += v0.z * m0 + v1.z * m1 + v2.z * m2 + v3.z * m3;
    acc.w += v0.w * m0 + v1.w * m1 + v2.w * m2 + v3.w * m3;
  }
  for (; j < e; ++j) {
    int c0 = csort[j];
    float m0 = MASKED ? mask[c0] : 1.0f;
    float4 v0 = in4[(size_t)c0 * 64 + lane];
    acc.x += v0.x * m0; acc.y += v0.y * m0; acc.z += v0.z * m0; acc.w += v0.w * m0;
  }
  float sc = 1.0f / (float)(e - s + 1);
  reinterpret_cast<float4*>(out)[(size_t)node * 64 + lane] =
      make_float4(acc.x * sc, acc.y * sc, acc.z * sc, acc.w * sc);
}

// ---------------- Y = (X .* DM) @ W1 (no bias/relu here), 64x64 tile ----------------
__global__ __launch_bounds__(256) void k_gemm(const float* __restrict__ X,
                                              const float* __restrict__ DM,
                                              const float* __restrict__ W,
                                              float* __restrict__ Z) {
  __shared__ float As[64][33];
  __shared__ float Ws[32][64];
  int tid = threadIdx.x;
  int row0 = blockIdx.x * 64;
  int col0 = blockIdx.y * 64;
  int ty = tid >> 4, tx = tid & 15;
  int arow = tid >> 2, acol = (tid & 3) * 8;
  int wrow = tid >> 3, wcol = (tid & 7) * 8;
  float acc[4][4] = {};
  for (int kk = 0; kk < FF; kk += 32) {
    float4 a0, a1;
    int gr = row0 + arow;
    if (gr < NN) {
      const float* ap = X + (size_t)gr * FF + kk + acol;
      const float* dp = DM + (size_t)gr * FF + kk + acol;
      float4 xa = *reinterpret_cast<const float4*>(ap);
      float4 xb = *reinterpret_cast<const float4*>(ap + 4);
      float4 da = *reinterpret_cast<const float4*>(dp);
      float4 db = *reinterpret_cast<const float4*>(dp + 4);
      a0 = make_float4(xa.x * da.x, xa.y * da.y, xa.z * da.z, xa.w * da.w);
      a1 = make_float4(xb.x * db.x, xb.y * db.y, xb.z * db.z, xb.w * db.w);
    } else {
      a0 = make_float4(0.f, 0.f, 0.f, 0.f); a1 = a0;
    }
    As[arow][acol + 0] = a0.x; As[arow][acol + 1] = a0.y;
    As[arow][acol + 2] = a0.z; As[arow][acol + 3] = a0.w;
    As[arow][acol + 4] = a1.x; As[arow][acol + 5] = a1.y;
    As[arow][acol + 6] = a1.z; As[arow][acol + 7] = a1.w;
    const float* wp = W + (size_t)(kk + wrow) * HH + col0 + wcol;
    *reinterpret_cast<float4*>(&Ws[wrow][wcol]) = *reinterpret_cast<const float4*>(wp);
    *reinterpret_cast<float4*>(&Ws[wrow][wcol + 4]) = *reinterpret_cast<const float4*>(wp + 4);
    __syncthreads();
#pragma unroll
    for (int k = 0; k < 32; ++k) {
      float av[4], wv[4];
#pragma unroll
      for (int i = 0; i < 4; ++i) av[i] = As[ty * 4 + i][k];
#pragma unroll
      for (int j = 0; j < 4; ++j) wv[j] = Ws[k][tx * 4 + j];
#pragma unroll
      for (int i = 0; i < 4; ++i)
#pragma unroll
        for (int j = 0; j < 4; ++j) acc[i][j] += av[i] * wv[j];
    }
    __syncthreads();
  }
#pragma unroll
  for (int i = 0; i < 4; ++i) {
    int r = row0 + ty * 4 + i;
    if (r < NN) {
      float4 o = make_float4(acc[i][0], acc[i][1], acc[i][2], acc[i][3]);
      *reinterpret_cast<float4*>(&Z[(size_t)r * HH + col0 + tx * 4]) = o;
    }
  }
}

// ---------------- strip-parallel pooled partial sums of relu(z + b1) ----------------
__global__ __launch_bounds__(256) void k_pool(const float* __restrict__ z,
                                              const int* __restrict__ bptr,
                                              const float* __restrict__ b1,
                                              float* __restrict__ part) {
  int b = blockIdx.x, s = blockIdx.y, col = threadIdx.x;
  int st = bptr[b], en = bptr[b + 1];
  int cnt = en - st;
  int per = (cnt + SS - 1) / SS;
  int rs = st + s * per;
  int re = rs + per; if (re > en) re = en;
  float bias = b1[col];
  float acc = 0.f;
  for (int r = rs; r < re; ++r) acc += fmaxf(z[(size_t)r * HH + col] + bias, 0.f);
  part[((size_t)s * BB + b) * HH + col] = acc;
}

// ---------------- head: meanpool -> @W2+b2 -> @Wc+bc -> softmax ----------------
__global__ __launch_bounds__(256) void k_head(const float* __restrict__ part,
                                              const int* __restrict__ bptr,
                                              const float* __restrict__ W2,
                                              const float* __restrict__ b2,
                                              const float* __restrict__ Wc,
                                              const float* __restrict__ bc,
                                              float* __restrict__ probs,
                                              float* __restrict__ logits) {
  int v = blockIdx.x / BB;
  int b = blockIdx.x % BB;
  int h = threadIdx.x;
  __shared__ float mr[HH];
  __shared__ float vr[HH];
  __shared__ float scs[CC];
  float acc = 0.f;
  for (int s = 0; s < SS; ++s)
    acc += part[(((size_t)v * SS + s) * BB + b) * HH + h];
  int cnt = bptr[b + 1] - bptr[b]; if (cnt < 1) cnt = 1;
  mr[h] = acc / (float)cnt;
  __syncthreads();
  float a = b2[h];
  for (int k = 0; k < HH; ++k) a += mr[k] * W2[k * HH + h];
  vr[h] = a;
  __syncthreads();
  if (h < CC) {
    float t = bc[h];
    for (int k = 0; k < HH; ++k) t += vr[k] * Wc[k * CC + h];
    scs[h] = t;
  }
  __syncthreads();
  if (h < CC) {
    float m = scs[0];
    for (int c = 1; c < CC; ++c) m = fmaxf(m, scs[c]);
    float den = 0.f;
    for (int c = 0; c < CC; ++c) den += expf(scs[c] - m);
    float p = expf(scs[h] - m) / den;
    probs[((size_t)v * BB + b) * CC + h] = p;
    if (v == 0) logits[b * CC + h] = scs[h];
  }
}

// ---------------- loss: consistency + entropy ----------------
__global__ __launch_bounds__(256) void k_loss(const float* __restrict__ probs, float* __restrict__ out) {
  __shared__ float mp[BB * CC];
  __shared__ float red[8];
  int tid = threadIdx.x;
  float ent = 0.f;
  for (int i = tid; i < BB * CC; i += 256) {
    float m = 0.25f * (probs[i] + probs[BB * CC + i] + probs[2 * BB * CC + i] + probs[3 * BB * CC + i]);
    mp[i] = m;
    ent += m * logf(m + 1e-8f);
  }
  __syncthreads();
  float cons = 0.f;
  for (int i = tid; i < VV * BB * CC; i += 256) {
    float d = probs[i] - mp[i % (BB * CC)];
    cons += d * d;
  }
  for (int o = 32; o > 0; o >>= 1) {
    cons += __shfl_down(cons, o, 64);
    ent += __shfl_down(ent, o, 64);
  }
  int wid = tid >> 6, lane = tid & 63;
  if (lane == 0) { red[wid] = cons; red[4 + wid] = ent; }
  __syncthreads();
  if (tid == 0) {
    float c = red[0] + red[1] + red[2] + red[3];
    float e2 = red[4] + red[5] + red[6] + red[7];
    out[0] = c / (float)(VV * BB) - e2 / (float)BB;
  }
}

extern "C" void kernel_launch(void* const* d_in, const int* in_sizes, int n_in,
                              void* d_out, int out_size, void* d_ws, size_t ws_size,
                              hipStream_t stream) {
  const float* x     = (const float*)d_in[0];
  const int*   erow  = (const int*)d_in[1];          // edge_index[0]
  const int*   ecol  = ((const int*)d_in[1]) + EE;   // edge_index[1]
  const int*   batch = (const int*)d_in[2];
  const float* dm    = (const float*)d_in[3];
  const float* nmask = (const float*)d_in[4];
  const float* W1    = (const float*)d_in[5];
  const float* b1    = (const float*)d_in[6];
  const float* W2    = (const float*)d_in[7];
  const float* b2    = (const float*)d_in[8];
  const float* Wc    = (const float*)d_in[9];
  const float* bc    = (const float*)d_in[10];
  float* out = (float*)d_out;

  char* ws = (char*)d_ws;
  size_t off = 0;
  auto carve = [&](size_t bytes) -> char* {
    char* p = ws + off;
    off = (off + bytes + 255) & ~(size_t)255;
    return p;
  };
  // small buffers first (common to both paths)
  float* part  = (float*)carve((size_t)VV * SS * BB * HH * 4);
  int*   deg   = (int*)carve((size_t)NN * 4);
  int*   fill  = (int*)carve((size_t)NN * 4);
  int*   rptr  = (int*)carve((size_t)(NN + 1) * 4);
  int*   csort = (int*)carve((size_t)EE * 4);
  int*   bptr  = (int*)carve((size_t)(BB + 1) * 4);
  float* probs = (float*)carve((size_t)VV * BB * CC * 4);

  const size_t NF = (size_t)NN * FF * 4;  // 51.2 MB
  size_t remaining = (ws_size > off) ? (ws_size - off) : 0;
  bool merged = remaining >= (NF + 256) * (VV + 1) + 1024;

  hipMemsetAsync(deg, 0, (size_t)NN * 4, stream);
  hipMemsetAsync(fill, 0, (size_t)NN * 4, stream);

  k_deg<<<(EE + 255) / 256, 256, 0, stream>>>(erow, deg);
  k_scan<<<1, 256, 0, stream>>>(deg, rptr);
  k_scatter<<<(EE + 255) / 256, 256, 0, stream>>>(erow, ecol, rptr, fill, csort);
  k_bptr<<<1, 256, 0, stream>>>(batch, bptr);

  if (merged) {
    float* y  = (float*)carve(NF);
    float* h1 = (float*)carve(NF * VV);
    k_gemm<<<dim3((NN + 63) / 64, HH / 64), 256, 0, stream>>>(x, dm, W1, y);
    k_prop1<<<(NN + 3) / 4, 256, 0, stream>>>(y, h1, rptr, csort, nmask);
    for (int v = 0; v < VV; ++v) {
      float* hv = h1 + (size_t)v * NN * FF;
      k_prop<false><<<(NN + 3) / 4, 256, 0, stream>>>(hv, y, rptr, csort, nullptr);
      k_prop<false><<<(NN + 3) / 4, 256, 0, stream>>>(y, hv, rptr, csort, nullptr);
      k_pool<<<dim3(BB, SS), 256, 0, stream>>>(hv, bptr, b1, part + (size_t)v * SS * BB * HH);
    }
  } else {
    float* y    = (float*)carve(NF);
    float* buf0 = (float*)carve(NF);
    float* buf1 = (float*)carve(NF);
    k_gemm<<<dim3((NN + 63) / 64, HH / 64), 256, 0, stream>>>(x, dm, W1, y);
    for (int v = 0; v < VV; ++v) {
      const float* mask = nmask + (size_t)v * NN;
      k_prop<true><<<(NN + 3) / 4, 256, 0, stream>>>(y, buf0, rptr, csort, mask);
      k_prop<false><<<(NN + 3) / 4, 256, 0, stream>>>(buf0, buf1, rptr, csort, nullptr);
      k_prop<false><<<(NN + 3) / 4, 256, 0, stream>>>(buf1, buf0, rptr, csort, nullptr);
      k_pool<<<dim3(BB, SS), 256, 0, stream>>>(buf0, bptr, b1, part + (size_t)v * SS * BB * HH);
    }
  }
  k_head<<<VV * BB, 256, 0, stream>>>(part, bptr, W2, b2, Wc, bc, probs, out);
  k_loss<<<1, 256, 0, stream>>>(probs, out + BB * CC);
}

// Round 3
// 1010.619 us; speedup vs baseline: 2.1921x; 1.5626x over previous
//
#include <hip/hip_runtime.h>
#include <hip/hip_bf16.h>
#include <hip/hip_fp16.h>

#define NN 50000
#define EE 800000
#define FF 256
#define HH 256
#define CC 10
#define BB 128
#define VV 4
#define SS 16   // pooling strips per batch

// fp16 pack/unpack helpers (accumulate fp32, store fp16)
__device__ inline float2 h2f(unsigned int u) {
  __half2 h = *reinterpret_cast<__half2*>(&u);
  return __half22float2(h);
}
__device__ inline unsigned int f2h(float a, float b) {
  __half2 h = __floats2half2_rn(a, b);
  return *reinterpret_cast<unsigned int*>(&h);
}

// ---------------- degree count (by row) ----------------
__global__ __launch_bounds__(256) void k_deg(const int* __restrict__ row, int* __restrict__ deg) {
  int i = blockIdx.x * 256 + threadIdx.x;
  if (i < EE) atomicAdd(&deg[row[i]], 1);
}

// ---------------- exclusive scan -> row_ptr ----------------
__global__ __launch_bounds__(256) void k_scan(const int* __restrict__ deg, int* __restrict__ rptr) {
  __shared__ int sums[256];
  int tid = threadIdx.x;
  const int chunk = (NN + 255) / 256;
  int st = tid * chunk;
  int en = st + chunk; if (en > NN) en = NN;
  int s = 0;
  for (int i = st; i < en; ++i) s += deg[i];
  sums[tid] = s;
  __syncthreads();
  if (tid == 0) {
    int run = 0;
    for (int i = 0; i < 256; ++i) { int t = sums[i]; sums[i] = run; run += t; }
  }
  __syncthreads();
  int run = sums[tid];
  for (int i = st; i < en; ++i) { rptr[i] = run; run += deg[i]; }
  if (tid == 255) rptr[NN] = run;
}

// ---------------- scatter edges into CSR ----------------
__global__ __launch_bounds__(256) void k_scatter(const int* __restrict__ row,
                                                 const int* __restrict__ col,
                                                 const int* __restrict__ rptr,
                                                 int* __restrict__ fill,
                                                 int* __restrict__ csort) {
  int i = blockIdx.x * 256 + threadIdx.x;
  if (i < EE) {
    int r = row[i];
    int p = rptr[r] + atomicAdd(&fill[r], 1);
    csort[p] = col[i];
  }
}

// ---------------- batch_ptr via binary search (batch sorted) ----------------
__global__ __launch_bounds__(256) void k_bptr(const int* __restrict__ batch, int* __restrict__ bptr) {
  int b = threadIdx.x;
  if (b > BB) return;
  int lo = 0, hi = NN;
  while (lo < hi) { int mid = (lo + hi) >> 1; if (batch[mid] < b) lo = mid + 1; else hi = mid; }
  bptr[b] = lo;
}

// ---------------- hop1 merged over 4 views (fp16 in/out, fp32 accum) ----------------
__global__ __launch_bounds__(256) void k_prop1(const __half* __restrict__ y,
                                               __half* __restrict__ h1,
                                               const int* __restrict__ rptr,
                                               const int* __restrict__ csort,
                                               const float* __restrict__ nmask) {
  int node = blockIdx.x * 4 + (threadIdx.x >> 6);
  if (node >= NN) return;
  int lane = threadIdx.x & 63;
  const uint2* in2 = reinterpret_cast<const uint2*>(y);
  int s = rptr[node], e = rptr[node + 1];
  float4 a0, a1, a2, a3;
  {
    uint2 raw = in2[(size_t)node * 64 + lane];
    float2 lo = h2f(raw.x), hi = h2f(raw.y);
    float m0 = nmask[node], m1 = nmask[NN + node], m2 = nmask[2 * NN + node], m3 = nmask[3 * NN + node];
    a0 = make_float4(lo.x * m0, lo.y * m0, hi.x * m0, hi.y * m0);
    a1 = make_float4(lo.x * m1, lo.y * m1, hi.x * m1, hi.y * m1);
    a2 = make_float4(lo.x * m2, lo.y * m2, hi.x * m2, hi.y * m2);
    a3 = make_float4(lo.x * m3, lo.y * m3, hi.x * m3, hi.y * m3);
  }
  int j = s;
  for (; j + 1 < e; j += 2) {
    int c0 = csort[j], c1 = csort[j + 1];
    uint2 r0 = in2[(size_t)c0 * 64 + lane];
    uint2 r1 = in2[(size_t)c1 * 64 + lane];
    float2 l0 = h2f(r0.x), u0 = h2f(r0.y);
    float2 l1 = h2f(r1.x), u1 = h2f(r1.y);
    float p0 = nmask[c0], p1 = nmask[NN + c0], p2 = nmask[2 * NN + c0], p3 = nmask[3 * NN + c0];
    float q0 = nmask[c1], q1 = nmask[NN + c1], q2 = nmask[2 * NN + c1], q3 = nmask[3 * NN + c1];
    a0.x += l0.x * p0 + l1.x * q0; a0.y += l0.y * p0 + l1.y * q0;
    a0.z += u0.x * p0 + u1.x * q0; a0.w += u0.y * p0 + u1.y * q0;
    a1.x += l0.x * p1 + l1.x * q1; a1.y += l0.y * p1 + l1.y * q1;
    a1.z += u0.x * p1 + u1.x * q1; a1.w += u0.y * p1 + u1.y * q1;
    a2.x += l0.x * p2 + l1.x * q2; a2.y += l0.y * p2 + l1.y * q2;
    a2.z += u0.x * p2 + u1.x * q2; a2.w += u0.y * p2 + u1.y * q2;
    a3.x += l0.x * p3 + l1.x * q3; a3.y += l0.y * p3 + l1.y * q3;
    a3.z += u0.x * p3 + u1.x * q3; a3.w += u0.y * p3 + u1.y * q3;
  }
  if (j < e) {
    int c0 = csort[j];
    uint2 r0 = in2[(size_t)c0 * 64 + lane];
    float2 l0 = h2f(r0.x), u0 = h2f(r0.y);
    float p0 = nmask[c0], p1 = nmask[NN + c0], p2 = nmask[2 * NN + c0], p3 = nmask[3 * NN + c0];
    a0.x += l0.x * p0; a0.y += l0.y * p0; a0.z += u0.x * p0; a0.w += u0.y * p0;
    a1.x += l0.x * p1; a1.y += l0.y * p1; a1.z += u0.x * p1; a1.w += u0.y * p1;
    a2.x += l0.x * p2; a2.y += l0.y * p2; a2.z += u0.x * p2; a2.w += u0.y * p2;
    a3.x += l0.x * p3; a3.y += l0.y * p3; a3.z += u0.x * p3; a3.w += u0.y * p3;
  }
  float sc = 1.0f / (float)(e - s + 1);
  uint2* o = reinterpret_cast<uint2*>(h1);
  size_t base = (size_t)node * 64 + lane;
  o[base] = make_uint2(f2h(a0.x * sc, a0.y * sc), f2h(a0.z * sc, a0.w * sc));
  o[(size_t)NN * 64 + base] = make_uint2(f2h(a1.x * sc, a1.y * sc), f2h(a1.z * sc, a1.w * sc));
  o[(size_t)2 * NN * 64 + base] = make_uint2(f2h(a2.x * sc, a2.y * sc), f2h(a2.z * sc, a2.w * sc));
  o[(size_t)3 * NN * 64 + base] = make_uint2(f2h(a3.x * sc, a3.y * sc), f2h(a3.z * sc, a3.w * sc));
}

// ---------------- propagation hop (fp16 in/out, fp32 accum) ----------------
__global__ __launch_bounds__(256) void k_prop(const __half* __restrict__ in,
                                              __half* __restrict__ out,
                                              const int* __restrict__ rptr,
                                              const int* __restrict__ csort) {
  int node = blockIdx.x * 4 + (threadIdx.x >> 6);
  if (node >= NN) return;
  int lane = threadIdx.x & 63;
  const uint2* in2 = reinterpret_cast<const uint2*>(in);
  int s = rptr[node], e = rptr[node + 1];
  float4 acc;
  {
    uint2 raw = in2[(size_t)node * 64 + lane];
    float2 lo = h2f(raw.x), hi = h2f(raw.y);
    acc = make_float4(lo.x, lo.y, hi.x, hi.y);
  }
  int j = s;
  for (; j + 3 < e; j += 4) {
    int c0 = csort[j], c1 = csort[j + 1], c2 = csort[j + 2], c3 = csort[j + 3];
    uint2 r0 = in2[(size_t)c0 * 64 + lane];
    uint2 r1 = in2[(size_t)c1 * 64 + lane];
    uint2 r2 = in2[(size_t)c2 * 64 + lane];
    uint2 r3 = in2[(size_t)c3 * 64 + lane];
    float2 l0 = h2f(r0.x), u0 = h2f(r0.y);
    float2 l1 = h2f(r1.x), u1 = h2f(r1.y);
    float2 l2 = h2f(r2.x), u2 = h2f(r2.y);
    float2 l3 = h2f(r3.x), u3 = h2f(r3.y);
    acc.x += l0.x + l1.x + l2.x + l3.x;
    acc.y += l0.y + l1.y + l2.y + l3.y;
    acc.z += u0.x + u1.x + u2.x + u3.x;
    acc.w += u0.y + u1.y + u2.y + u3.y;
  }
  for (; j < e; ++j) {
    int c0 = csort[j];
    uint2 r0 = in2[(size_t)c0 * 64 + lane];
    float2 l0 = h2f(r0.x), u0 = h2f(r0.y);
    acc.x += l0.x; acc.y += l0.y; acc.z += u0.x; acc.w += u0.y;
  }
  float sc = 1.0f / (float)(e - s + 1);
  reinterpret_cast<uint2*>(out)[(size_t)node * 64 + lane] =
      make_uint2(f2h(acc.x * sc, acc.y * sc), f2h(acc.z * sc, acc.w * sc));
}

// ---------------- Y = (X .* DM) @ W1 -> fp16, 64x64 tile ----------------
__global__ __launch_bounds__(256) void k_gemm(const float* __restrict__ X,
                                              const float* __restrict__ DM,
                                              const float* __restrict__ W,
                                              __half* __restrict__ Z) {
  __shared__ float As[64][33];
  __shared__ float Ws[32][64];
  int tid = threadIdx.x;
  int row0 = blockIdx.x * 64;
  int col0 = blockIdx.y * 64;
  int ty = tid >> 4, tx = tid & 15;
  int arow = tid >> 2, acol = (tid & 3) * 8;
  int wrow = tid >> 3, wcol = (tid & 7) * 8;
  float acc[4][4] = {};
  for (int kk = 0; kk < FF; kk += 32) {
    float4 a0, a1;
    int gr = row0 + arow;
    if (gr < NN) {
      const float* ap = X + (size_t)gr * FF + kk + acol;
      const float* dp = DM + (size_t)gr * FF + kk + acol;
      float4 xa = *reinterpret_cast<const float4*>(ap);
      float4 xb = *reinterpret_cast<const float4*>(ap + 4);
      float4 da = *reinterpret_cast<const float4*>(dp);
      float4 db = *reinterpret_cast<const float4*>(dp + 4);
      a0 = make_float4(xa.x * da.x, xa.y * da.y, xa.z * da.z, xa.w * da.w);
      a1 = make_float4(xb.x * db.x, xb.y * db.y, xb.z * db.z, xb.w * db.w);
    } else {
      a0 = make_float4(0.f, 0.f, 0.f, 0.f); a1 = a0;
    }
    As[arow][acol + 0] = a0.x; As[arow][acol + 1] = a0.y;
    As[arow][acol + 2] = a0.z; As[arow][acol + 3] = a0.w;
    As[arow][acol + 4] = a1.x; As[arow][acol + 5] = a1.y;
    As[arow][acol + 6] = a1.z; As[arow][acol + 7] = a1.w;
    const float* wp = W + (size_t)(kk + wrow) * HH + col0 + wcol;
    *reinterpret_cast<float4*>(&Ws[wrow][wcol]) = *reinterpret_cast<const float4*>(wp);
    *reinterpret_cast<float4*>(&Ws[wrow][wcol + 4]) = *reinterpret_cast<const float4*>(wp + 4);
    __syncthreads();
#pragma unroll
    for (int k = 0; k < 32; ++k) {
      float av[4], wv[4];
#pragma unroll
      for (int i = 0; i < 4; ++i) av[i] = As[ty * 4 + i][k];
#pragma unroll
      for (int j = 0; j < 4; ++j) wv[j] = Ws[k][tx * 4 + j];
#pragma unroll
      for (int i = 0; i < 4; ++i)
#pragma unroll
        for (int j = 0; j < 4; ++j) acc[i][j] += av[i] * wv[j];
    }
    __syncthreads();
  }
#pragma unroll
  for (int i = 0; i < 4; ++i) {
    int r = row0 + ty * 4 + i;
    if (r < NN) {
      *reinterpret_cast<uint2*>(&Z[(size_t)r * HH + col0 + tx * 4]) =
          make_uint2(f2h(acc[i][0], acc[i][1]), f2h(acc[i][2], acc[i][3]));
    }
  }
}

// ---------------- strip-parallel pooled partial sums of relu(z + b1), fp16 in ----------------
__global__ __launch_bounds__(256) void k_pool(const __half* __restrict__ z,
                                              const int* __restrict__ bptr,
                                              const float* __restrict__ b1,
                                              float* __restrict__ part) {
  int b = blockIdx.x, s = blockIdx.y, col = threadIdx.x;
  int st = bptr[b], en = bptr[b + 1];
  int cnt = en - st;
  int per = (cnt + SS - 1) / SS;
  int rs = st + s * per;
  int re = rs + per; if (re > en) re = en;
  float bias = b1[col];
  float acc = 0.f;
  for (int r = rs; r < re; ++r)
    acc += fmaxf(__half2float(z[(size_t)r * HH + col]) + bias, 0.f);
  part[((size_t)s * BB + b) * HH + col] = acc;
}

// ---------------- head: meanpool -> @W2+b2 -> @Wc+bc -> softmax ----------------
__global__ __launch_bounds__(256) void k_head(const float* __restrict__ part,
                                              const int* __restrict__ bptr,
                                              const float* __restrict__ W2,
                                              const float* __restrict__ b2,
                                              const float* __restrict__ Wc,
                                              const float* __restrict__ bc,
                                              float* __restrict__ probs,
                                              float* __restrict__ logits) {
  int v = blockIdx.x / BB;
  int b = blockIdx.x % BB;
  int h = threadIdx.x;
  __shared__ float mr[HH];
  __shared__ float vr[HH];
  __shared__ float scs[CC];
  float acc = 0.f;
  for (int s = 0; s < SS; ++s)
    acc += part[(((size_t)v * SS + s) * BB + b) * HH + h];
  int cnt = bptr[b + 1] - bptr[b]; if (cnt < 1) cnt = 1;
  mr[h] = acc / (float)cnt;
  __syncthreads();
  float a = b2[h];
  for (int k = 0; k < HH; ++k) a += mr[k] * W2[k * HH + h];
  vr[h] = a;
  __syncthreads();
  if (h < CC) {
    float t = bc[h];
    for (int k = 0; k < HH; ++k) t += vr[k] * Wc[k * CC + h];
    scs[h] = t;
  }
  __syncthreads();
  if (h < CC) {
    float m = scs[0];
    for (int c = 1; c < CC; ++c) m = fmaxf(m, scs[c]);
    float den = 0.f;
    for (int c = 0; c < CC; ++c) den += expf(scs[c] - m);
    float p = expf(scs[h] - m) / den;
    probs[((size_t)v * BB + b) * CC + h] = p;
    if (v == 0) logits[b * CC + h] = scs[h];
  }
}

// ---------------- loss: consistency + entropy ----------------
__global__ __launch_bounds__(256) void k_loss(const float* __restrict__ probs, float* __restrict__ out) {
  __shared__ float mp[BB * CC];
  __shared__ float red[8];
  int tid = threadIdx.x;
  float ent = 0.f;
  for (int i = tid; i < BB * CC; i += 256) {
    float m = 0.25f * (probs[i] + probs[BB * CC + i] + probs[2 * BB * CC + i] + probs[3 * BB * CC + i]);
    mp[i] = m;
    ent += m * logf(m + 1e-8f);
  }
  __syncthreads();
  float cons = 0.f;
  for (int i = tid; i < VV * BB * CC; i += 256) {
    float d = probs[i] - mp[i % (BB * CC)];
    cons += d * d;
  }
  for (int o = 32; o > 0; o >>= 1) {
    cons += __shfl_down(cons, o, 64);
    ent += __shfl_down(ent, o, 64);
  }
  int wid = tid >> 6, lane = tid & 63;
  if (lane == 0) { red[wid] = cons; red[4 + wid] = ent; }
  __syncthreads();
  if (tid == 0) {
    float c = red[0] + red[1] + red[2] + red[3];
    float e2 = red[4] + red[5] + red[6] + red[7];
    out[0] = c / (float)(VV * BB) - e2 / (float)BB;
  }
}

extern "C" void kernel_launch(void* const* d_in, const int* in_sizes, int n_in,
                              void* d_out, int out_size, void* d_ws, size_t ws_size,
                              hipStream_t stream) {
  const float* x     = (const float*)d_in[0];
  const int*   erow  = (const int*)d_in[1];          // edge_index[0]
  const int*   ecol  = ((const int*)d_in[1]) + EE;   // edge_index[1]
  const int*   batch = (const int*)d_in[2];
  const float* dm    = (const float*)d_in[3];
  const float* nmask = (const float*)d_in[4];
  const float* W1    = (const float*)d_in[5];
  const float* b1    = (const float*)d_in[6];
  const float* W2    = (const float*)d_in[7];
  const float* b2    = (const float*)d_in[8];
  const float* Wc    = (const float*)d_in[9];
  const float* bc    = (const float*)d_in[10];
  float* out = (float*)d_out;

  char* ws = (char*)d_ws;
  size_t off = 0;
  auto carve = [&](size_t bytes) -> char* {
    char* p = ws + off;
    off = (off + bytes + 255) & ~(size_t)255;
    return p;
  };
  float* part  = (float*)carve((size_t)VV * SS * BB * HH * 4);
  int*   deg   = (int*)carve((size_t)NN * 4);
  int*   fill  = (int*)carve((size_t)NN * 4);
  int*   rptr  = (int*)carve((size_t)(NN + 1) * 4);
  int*   csort = (int*)carve((size_t)EE * 4);
  int*   bptr  = (int*)carve((size_t)(BB + 1) * 4);
  float* probs = (float*)carve((size_t)VV * BB * CC * 4);

  const size_t NFh = (size_t)NN * FF * 2;  // 25.6 MB fp16 node-feature plane
  __half* y  = (__half*)carve(NFh);
  __half* h1 = (__half*)carve(NFh * VV);

  hipMemsetAsync(deg, 0, (size_t)NN * 4, stream);
  hipMemsetAsync(fill, 0, (size_t)NN * 4, stream);

  k_deg<<<(EE + 255) / 256, 256, 0, stream>>>(erow, deg);
  k_scan<<<1, 256, 0, stream>>>(deg, rptr);
  k_scatter<<<(EE + 255) / 256, 256, 0, stream>>>(erow, ecol, rptr, fill, csort);
  k_bptr<<<1, 256, 0, stream>>>(batch, bptr);

  k_gemm<<<dim3((NN + 63) / 64, HH / 64), 256, 0, stream>>>(x, dm, W1, y);
  k_prop1<<<(NN + 3) / 4, 256, 0, stream>>>(y, h1, rptr, csort, nmask);
  for (int v = 0; v < VV; ++v) {
    __half* hv = h1 + (size_t)v * NN * FF;
    k_prop<<<(NN + 3) / 4, 256, 0, stream>>>(hv, y, rptr, csort);
    k_prop<<<(NN + 3) / 4, 256, 0, stream>>>(y, hv, rptr, csort);
    k_pool<<<dim3(BB, SS), 256, 0, stream>>>(hv, bptr, b1, part + (size_t)v * SS * BB * HH);
  }
  k_head<<<VV * BB, 256, 0, stream>>>(part, bptr, W2, b2, Wc, bc, probs, out);
  k_loss<<<1, 256, 0, stream>>>(probs, out + BB * CC);
}

// Round 4
// 989.261 us; speedup vs baseline: 2.2395x; 1.0216x over previous
//
#include <hip/hip_runtime.h>
#include <hip/hip_bf16.h>
#include <hip/hip_fp16.h>

#define NN 50000
#define EE 800000
#define FF 256
#define HH 256
#define CC 10
#define BB 128
#define VV 4
#define SS 16   // pooling strips per batch

// fp16 pack/unpack helpers (accumulate fp32, store fp16)
__device__ inline float2 h2f(unsigned int u) {
  __half2 h = *reinterpret_cast<__half2*>(&u);
  return __half22float2(h);
}
__device__ inline unsigned int f2h(float a, float b) {
  __half2 h = __floats2half2_rn(a, b);
  return *reinterpret_cast<unsigned int*>(&h);
}

// ---------------- degree count (by row) ----------------
__global__ __launch_bounds__(256) void k_deg(const int* __restrict__ row, int* __restrict__ deg) {
  int i = blockIdx.x * 256 + threadIdx.x;
  if (i < EE) atomicAdd(&deg[row[i]], 1);
}

// ---------------- exclusive scan -> row_ptr ----------------
__global__ __launch_bounds__(256) void k_scan(const int* __restrict__ deg, int* __restrict__ rptr) {
  __shared__ int sums[256];
  int tid = threadIdx.x;
  const int chunk = (NN + 255) / 256;
  int st = tid * chunk;
  int en = st + chunk; if (en > NN) en = NN;
  int s = 0;
  for (int i = st; i < en; ++i) s += deg[i];
  sums[tid] = s;
  __syncthreads();
  if (tid == 0) {
    int run = 0;
    for (int i = 0; i < 256; ++i) { int t = sums[i]; sums[i] = run; run += t; }
  }
  __syncthreads();
  int run = sums[tid];
  for (int i = st; i < en; ++i) { rptr[i] = run; run += deg[i]; }
  if (tid == 255) rptr[NN] = run;
}

// ---------------- scatter edges into CSR ----------------
__global__ __launch_bounds__(256) void k_scatter(const int* __restrict__ row,
                                                 const int* __restrict__ col,
                                                 const int* __restrict__ rptr,
                                                 int* __restrict__ fill,
                                                 int* __restrict__ csort) {
  int i = blockIdx.x * 256 + threadIdx.x;
  if (i < EE) {
    int r = row[i];
    int p = rptr[r] + atomicAdd(&fill[r], 1);
    csort[p] = col[i];
  }
}

// ---------------- batch_ptr via binary search (batch sorted) ----------------
__global__ __launch_bounds__(256) void k_bptr(const int* __restrict__ batch, int* __restrict__ bptr) {
  int b = threadIdx.x;
  if (b > BB) return;
  int lo = 0, hi = NN;
  while (lo < hi) { int mid = (lo + hi) >> 1; if (batch[mid] < b) lo = mid + 1; else hi = mid; }
  bptr[b] = lo;
}

// ---------------- hop1 merged over 4 views (fp16 in/out, fp32 accum) ----------------
__global__ __launch_bounds__(256) void k_prop1(const __half* __restrict__ y,
                                               __half* __restrict__ h1,
                                               const int* __restrict__ rptr,
                                               const int* __restrict__ csort,
                                               const float* __restrict__ nmask) {
  int node = blockIdx.x * 4 + (threadIdx.x >> 6);
  if (node >= NN) return;
  int lane = threadIdx.x & 63;
  const uint2* in2 = reinterpret_cast<const uint2*>(y);
  int s = rptr[node], e = rptr[node + 1];
  float4 a0, a1, a2, a3;
  {
    uint2 raw = in2[(size_t)node * 64 + lane];
    float2 lo = h2f(raw.x), hi = h2f(raw.y);
    float m0 = nmask[node], m1 = nmask[NN + node], m2 = nmask[2 * NN + node], m3 = nmask[3 * NN + node];
    a0 = make_float4(lo.x * m0, lo.y * m0, hi.x * m0, hi.y * m0);
    a1 = make_float4(lo.x * m1, lo.y * m1, hi.x * m1, hi.y * m1);
    a2 = make_float4(lo.x * m2, lo.y * m2, hi.x * m2, hi.y * m2);
    a3 = make_float4(lo.x * m3, lo.y * m3, hi.x * m3, hi.y * m3);
  }
  int j = s;
  for (; j + 1 < e; j += 2) {
    int c0 = csort[j], c1 = csort[j + 1];
    uint2 r0 = in2[(size_t)c0 * 64 + lane];
    uint2 r1 = in2[(size_t)c1 * 64 + lane];
    float2 l0 = h2f(r0.x), u0 = h2f(r0.y);
    float2 l1 = h2f(r1.x), u1 = h2f(r1.y);
    float p0 = nmask[c0], p1 = nmask[NN + c0], p2 = nmask[2 * NN + c0], p3 = nmask[3 * NN + c0];
    float q0 = nmask[c1], q1 = nmask[NN + c1], q2 = nmask[2 * NN + c1], q3 = nmask[3 * NN + c1];
    a0.x += l0.x * p0 + l1.x * q0; a0.y += l0.y * p0 + l1.y * q0;
    a0.z += u0.x * p0 + u1.x * q0; a0.w += u0.y * p0 + u1.y * q0;
    a1.x += l0.x * p1 + l1.x * q1; a1.y += l0.y * p1 + l1.y * q1;
    a1.z += u0.x * p1 + u1.x * q1; a1.w += u0.y * p1 + u1.y * q1;
    a2.x += l0.x * p2 + l1.x * q2; a2.y += l0.y * p2 + l1.y * q2;
    a2.z += u0.x * p2 + u1.x * q2; a2.w += u0.y * p2 + u1.y * q2;
    a3.x += l0.x * p3 + l1.x * q3; a3.y += l0.y * p3 + l1.y * q3;
    a3.z += u0.x * p3 + u1.x * q3; a3.w += u0.y * p3 + u1.y * q3;
  }
  if (j < e) {
    int c0 = csort[j];
    uint2 r0 = in2[(size_t)c0 * 64 + lane];
    float2 l0 = h2f(r0.x), u0 = h2f(r0.y);
    float p0 = nmask[c0], p1 = nmask[NN + c0], p2 = nmask[2 * NN + c0], p3 = nmask[3 * NN + c0];
    a0.x += l0.x * p0; a0.y += l0.y * p0; a0.z += u0.x * p0; a0.w += u0.y * p0;
    a1.x += l0.x * p1; a1.y += l0.y * p1; a1.z += u0.x * p1; a1.w += u0.y * p1;
    a2.x += l0.x * p2; a2.y += l0.y * p2; a2.z += u0.x * p2; a2.w += u0.y * p2;
    a3.x += l0.x * p3; a3.y += l0.y * p3; a3.z += u0.x * p3; a3.w += u0.y * p3;
  }
  float sc = 1.0f / (float)(e - s + 1);
  uint2* o = reinterpret_cast<uint2*>(h1);
  size_t base = (size_t)node * 64 + lane;
  o[base] = make_uint2(f2h(a0.x * sc, a0.y * sc), f2h(a0.z * sc, a0.w * sc));
  o[(size_t)NN * 64 + base] = make_uint2(f2h(a1.x * sc, a1.y * sc), f2h(a1.z * sc, a1.w * sc));
  o[(size_t)2 * NN * 64 + base] = make_uint2(f2h(a2.x * sc, a2.y * sc), f2h(a2.z * sc, a2.w * sc));
  o[(size_t)3 * NN * 64 + base] = make_uint2(f2h(a3.x * sc, a3.y * sc), f2h(a3.z * sc, a3.w * sc));
}

// ---------------- propagation hop (fp16 in/out, fp32 accum) ----------------
__global__ __launch_bounds__(256) void k_prop(const __half* __restrict__ in,
                                              __half* __restrict__ out,
                                              const int* __restrict__ rptr,
                                              const int* __restrict__ csort) {
  int node = blockIdx.x * 4 + (threadIdx.x >> 6);
  if (node >= NN) return;
  int lane = threadIdx.x & 63;
  const uint2* in2 = reinterpret_cast<const uint2*>(in);
  int s = rptr[node], e = rptr[node + 1];
  float4 acc;
  {
    uint2 raw = in2[(size_t)node * 64 + lane];
    float2 lo = h2f(raw.x), hi = h2f(raw.y);
    acc = make_float4(lo.x, lo.y, hi.x, hi.y);
  }
  int j = s;
  for (; j + 3 < e; j += 4) {
    int c0 = csort[j], c1 = csort[j + 1], c2 = csort[j + 2], c3 = csort[j + 3];
    uint2 r0 = in2[(size_t)c0 * 64 + lane];
    uint2 r1 = in2[(size_t)c1 * 64 + lane];
    uint2 r2 = in2[(size_t)c2 * 64 + lane];
    uint2 r3 = in2[(size_t)c3 * 64 + lane];
    float2 l0 = h2f(r0.x), u0 = h2f(r0.y);
    float2 l1 = h2f(r1.x), u1 = h2f(r1.y);
    float2 l2 = h2f(r2.x), u2 = h2f(r2.y);
    float2 l3 = h2f(r3.x), u3 = h2f(r3.y);
    acc.x += l0.x + l1.x + l2.x + l3.x;
    acc.y += l0.y + l1.y + l2.y + l3.y;
    acc.z += u0.x + u1.x + u2.x + u3.x;
    acc.w += u0.y + u1.y + u2.y + u3.y;
  }
  for (; j < e; ++j) {
    int c0 = csort[j];
    uint2 r0 = in2[(size_t)c0 * 64 + lane];
    float2 l0 = h2f(r0.x), u0 = h2f(r0.y);
    acc.x += l0.x; acc.y += l0.y; acc.z += u0.x; acc.w += u0.y;
  }
  float sc = 1.0f / (float)(e - s + 1);
  reinterpret_cast<uint2*>(out)[(size_t)node * 64 + lane] =
      make_uint2(f2h(acc.x * sc, acc.y * sc), f2h(acc.z * sc, acc.w * sc));
}

// ---------------- fused hop3 + bias + relu + pool (atomic into part strips) ----------------
__global__ __launch_bounds__(256) void k_prop3(const __half* __restrict__ in,
                                               const int* __restrict__ rptr,
                                               const int* __restrict__ csort,
                                               const int* __restrict__ batch,
                                               const float* __restrict__ b1,
                                               float* __restrict__ part) {
  int w = threadIdx.x >> 6, lane = threadIdx.x & 63;
  int node = blockIdx.x * 4 + w;
  __shared__ float red[4][HH];
  __shared__ int bb[4];
  const uint2* in2 = reinterpret_cast<const uint2*>(in);
  int s = rptr[node], e = rptr[node + 1];
  float4 acc;
  {
    uint2 raw = in2[(size_t)node * 64 + lane];
    float2 lo = h2f(raw.x), hi = h2f(raw.y);
    acc = make_float4(lo.x, lo.y, hi.x, hi.y);
  }
  int j = s;
  for (; j + 3 < e; j += 4) {
    int c0 = csort[j], c1 = csort[j + 1], c2 = csort[j + 2], c3 = csort[j + 3];
    uint2 r0 = in2[(size_t)c0 * 64 + lane];
    uint2 r1 = in2[(size_t)c1 * 64 + lane];
    uint2 r2 = in2[(size_t)c2 * 64 + lane];
    uint2 r3 = in2[(size_t)c3 * 64 + lane];
    float2 l0 = h2f(r0.x), u0 = h2f(r0.y);
    float2 l1 = h2f(r1.x), u1 = h2f(r1.y);
    float2 l2 = h2f(r2.x), u2 = h2f(r2.y);
    float2 l3 = h2f(r3.x), u3 = h2f(r3.y);
    acc.x += l0.x + l1.x + l2.x + l3.x;
    acc.y += l0.y + l1.y + l2.y + l3.y;
    acc.z += u0.x + u1.x + u2.x + u3.x;
    acc.w += u0.y + u1.y + u2.y + u3.y;
  }
  for (; j < e; ++j) {
    int c0 = csort[j];
    uint2 r0 = in2[(size_t)c0 * 64 + lane];
    float2 l0 = h2f(r0.x), u0 = h2f(r0.y);
    acc.x += l0.x; acc.y += l0.y; acc.z += u0.x; acc.w += u0.y;
  }
  float sc = 1.0f / (float)(e - s + 1);
  float4 bv = *reinterpret_cast<const float4*>(&b1[lane * 4]);
  red[w][lane * 4 + 0] = fmaxf(acc.x * sc + bv.x, 0.f);
  red[w][lane * 4 + 1] = fmaxf(acc.y * sc + bv.y, 0.f);
  red[w][lane * 4 + 2] = fmaxf(acc.z * sc + bv.z, 0.f);
  red[w][lane * 4 + 3] = fmaxf(acc.w * sc + bv.w, 0.f);
  if (lane == 0) bb[w] = batch[node];
  __syncthreads();
  int strip = blockIdx.x & (SS - 1);
  if (bb[0] == bb[1] && bb[1] == bb[2] && bb[2] == bb[3]) {
    int col = threadIdx.x;
    float sum = red[0][col] + red[1][col] + red[2][col] + red[3][col];
    atomicAdd(&part[((size_t)strip * BB + bb[0]) * HH + col], sum);
  } else {
    int b = bb[w];
#pragma unroll
    for (int k = 0; k < 4; ++k)
      atomicAdd(&part[((size_t)strip * BB + b) * HH + lane * 4 + k], red[w][lane * 4 + k]);
  }
}

// ---------------- Y = (X .* DM) @ W1 -> fp16, 64x256 full-width tile ----------------
__global__ __launch_bounds__(256) void k_gemm(const float* __restrict__ X,
                                              const float* __restrict__ DM,
                                              const float* __restrict__ W,
                                              __half* __restrict__ Z) {
  __shared__ float As[64][33];
  __shared__ float Ws[32][258];
  int tid = threadIdx.x;
  int row0 = blockIdx.x * 64;
  int ty = tid >> 4, tx = tid & 15;       // 16x16 thread grid: 4 rows x 16 cols each
  int arow = tid >> 2, acol = (tid & 3) * 8;
  int wrow = tid >> 3, wlane = tid & 7;
  float acc[4][16] = {};
  for (int kk = 0; kk < FF; kk += 32) {
    // stage A (64 x 32, dropout fused)
    float4 a0, a1;
    int gr = row0 + arow;
    if (gr < NN) {
      const float* ap = X + (size_t)gr * FF + kk + acol;
      const float* dp = DM + (size_t)gr * FF + kk + acol;
      float4 xa = *reinterpret_cast<const float4*>(ap);
      float4 xb = *reinterpret_cast<const float4*>(ap + 4);
      float4 da = *reinterpret_cast<const float4*>(dp);
      float4 db = *reinterpret_cast<const float4*>(dp + 4);
      a0 = make_float4(xa.x * da.x, xa.y * da.y, xa.z * da.z, xa.w * da.w);
      a1 = make_float4(xb.x * db.x, xb.y * db.y, xb.z * db.z, xb.w * db.w);
    } else {
      a0 = make_float4(0.f, 0.f, 0.f, 0.f); a1 = a0;
    }
    As[arow][acol + 0] = a0.x; As[arow][acol + 1] = a0.y;
    As[arow][acol + 2] = a0.z; As[arow][acol + 3] = a0.w;
    As[arow][acol + 4] = a1.x; As[arow][acol + 5] = a1.y;
    As[arow][acol + 6] = a1.z; As[arow][acol + 7] = a1.w;
    // stage W (32 x 256): thread (wrow, wlane) loads 8 float4 at cols wlane*4 + 32q
    const float* wp = W + (size_t)(kk + wrow) * HH;
#pragma unroll
    for (int q = 0; q < 8; ++q) {
      int c = wlane * 4 + 32 * q;
      *reinterpret_cast<float4*>(&Ws[wrow][c]) = *reinterpret_cast<const float4*>(wp + c);
    }
    __syncthreads();
#pragma unroll 4
    for (int k = 0; k < 32; ++k) {
      float av[4];
#pragma unroll
      for (int i = 0; i < 4; ++i) av[i] = As[ty * 4 + i][k];
#pragma unroll
      for (int j = 0; j < 8; ++j) {
        float2 w2 = *reinterpret_cast<const float2*>(&Ws[k][tx * 2 + 32 * j]);
#pragma unroll
        for (int i = 0; i < 4; ++i) {
          acc[i][2 * j] += av[i] * w2.x;
          acc[i][2 * j + 1] += av[i] * w2.y;
        }
      }
    }
    __syncthreads();
  }
#pragma unroll
  for (int i = 0; i < 4; ++i) {
    int r = row0 + ty * 4 + i;
    if (r < NN) {
#pragma unroll
      for (int j = 0; j < 8; ++j) {
        *reinterpret_cast<unsigned int*>(&Z[(size_t)r * HH + tx * 2 + 32 * j]) =
            f2h(acc[i][2 * j], acc[i][2 * j + 1]);
      }
    }
  }
}

// ---------------- head: meanpool -> @W2+b2 -> @Wc+bc -> softmax ----------------
__global__ __launch_bounds__(256) void k_head(const float* __restrict__ part,
                                              const int* __restrict__ bptr,
                                              const float* __restrict__ W2,
                                              const float* __restrict__ b2,
                                              const float* __restrict__ Wc,
                                              const float* __restrict__ bc,
                                              float* __restrict__ probs,
                                              float* __restrict__ logits) {
  int v = blockIdx.x / BB;
  int b = blockIdx.x % BB;
  int h = threadIdx.x;
  __shared__ float mr[HH];
  __shared__ float vr[HH];
  __shared__ float scs[CC];
  float acc = 0.f;
  for (int s = 0; s < SS; ++s)
    acc += part[(((size_t)v * SS + s) * BB + b) * HH + h];
  int cnt = bptr[b + 1] - bptr[b]; if (cnt < 1) cnt = 1;
  mr[h] = acc / (float)cnt;
  __syncthreads();
  float a = b2[h];
  for (int k = 0; k < HH; ++k) a += mr[k] * W2[k * HH + h];
  vr[h] = a;
  __syncthreads();
  if (h < CC) {
    float t = bc[h];
    for (int k = 0; k < HH; ++k) t += vr[k] * Wc[k * CC + h];
    scs[h] = t;
  }
  __syncthreads();
  if (h < CC) {
    float m = scs[0];
    for (int c = 1; c < CC; ++c) m = fmaxf(m, scs[c]);
    float den = 0.f;
    for (int c = 0; c < CC; ++c) den += expf(scs[c] - m);
    float p = expf(scs[h] - m) / den;
    probs[((size_t)v * BB + b) * CC + h] = p;
    if (v == 0) logits[b * CC + h] = scs[h];
  }
}

// ---------------- loss: consistency + entropy ----------------
__global__ __launch_bounds__(256) void k_loss(const float* __restrict__ probs, float* __restrict__ out) {
  __shared__ float mp[BB * CC];
  __shared__ float red[8];
  int tid = threadIdx.x;
  float ent = 0.f;
  for (int i = tid; i < BB * CC; i += 256) {
    float m = 0.25f * (probs[i] + probs[BB * CC + i] + probs[2 * BB * CC + i] + probs[3 * BB * CC + i]);
    mp[i] = m;
    ent += m * logf(m + 1e-8f);
  }
  __syncthreads();
  float cons = 0.f;
  for (int i = tid; i < VV * BB * CC; i += 256) {
    float d = probs[i] - mp[i % (BB * CC)];
    cons += d * d;
  }
  for (int o = 32; o > 0; o >>= 1) {
    cons += __shfl_down(cons, o, 64);
    ent += __shfl_down(ent, o, 64);
  }
  int wid = tid >> 6, lane = tid & 63;
  if (lane == 0) { red[wid] = cons; red[4 + wid] = ent; }
  __syncthreads();
  if (tid == 0) {
    float c = red[0] + red[1] + red[2] + red[3];
    float e2 = red[4] + red[5] + red[6] + red[7];
    out[0] = c / (float)(VV * BB) - e2 / (float)BB;
  }
}

extern "C" void kernel_launch(void* const* d_in, const int* in_sizes, int n_in,
                              void* d_out, int out_size, void* d_ws, size_t ws_size,
                              hipStream_t stream) {
  const float* x     = (const float*)d_in[0];
  const int*   erow  = (const int*)d_in[1];          // edge_index[0]
  const int*   ecol  = ((const int*)d_in[1]) + EE;   // edge_index[1]
  const int*   batch = (const int*)d_in[2];
  const float* dm    = (const float*)d_in[3];
  const float* nmask = (const float*)d_in[4];
  const float* W1    = (const float*)d_in[5];
  const float* b1    = (const float*)d_in[6];
  const float* W2    = (const float*)d_in[7];
  const float* b2    = (const float*)d_in[8];
  const float* Wc    = (const float*)d_in[9];
  const float* bc    = (const float*)d_in[10];
  float* out = (float*)d_out;

  char* ws = (char*)d_ws;
  size_t off = 0;
  auto carve = [&](size_t bytes) -> char* {
    char* p = ws + off;
    off = (off + bytes + 255) & ~(size_t)255;
    return p;
  };
  float* part  = (float*)carve((size_t)VV * SS * BB * HH * 4);
  int*   deg   = (int*)carve((size_t)NN * 4);
  int*   fill  = (int*)carve((size_t)NN * 4);
  int*   rptr  = (int*)carve((size_t)(NN + 1) * 4);
  int*   csort = (int*)carve((size_t)EE * 4);
  int*   bptr  = (int*)carve((size_t)(BB + 1) * 4);
  float* probs = (float*)carve((size_t)VV * BB * CC * 4);

  const size_t NFh = (size_t)NN * FF * 2;  // 25.6 MB fp16 node-feature plane
  __half* y  = (__half*)carve(NFh);        // GEMM out; reused as hop2 temp
  __half* h1 = (__half*)carve(NFh * VV);

  hipMemsetAsync(deg, 0, (size_t)NN * 4, stream);
  hipMemsetAsync(fill, 0, (size_t)NN * 4, stream);
  hipMemsetAsync(part, 0, (size_t)VV * SS * BB * HH * 4, stream);

  k_deg<<<(EE + 255) / 256, 256, 0, stream>>>(erow, deg);
  k_scan<<<1, 256, 0, stream>>>(deg, rptr);
  k_scatter<<<(EE + 255) / 256, 256, 0, stream>>>(erow, ecol, rptr, fill, csort);
  k_bptr<<<1, 256, 0, stream>>>(batch, bptr);

  k_gemm<<<(NN + 63) / 64, 256, 0, stream>>>(x, dm, W1, y);
  k_prop1<<<(NN + 3) / 4, 256, 0, stream>>>(y, h1, rptr, csort, nmask);
  for (int v = 0; v < VV; ++v) {
    __half* hv = h1 + (size_t)v * NN * FF;
    k_prop<<<(NN + 3) / 4, 256, 0, stream>>>(hv, y, rptr, csort);          // hop2 -> y (reused)
    k_prop3<<<(NN + 3) / 4, 256, 0, stream>>>(y, rptr, csort, batch, b1,
                                              part + (size_t)v * SS * BB * HH);  // hop3+relu+pool
  }
  k_head<<<VV * BB, 256, 0, stream>>>(part, bptr, W2, b2, Wc, bc, probs, out);
  k_loss<<<1, 256, 0, stream>>>(probs, out + BB * CC);
}

// Round 5
// 944.552 us; speedup vs baseline: 2.3455x; 1.0473x over previous
//
#include <hip/hip_runtime.h>
#include <hip/hip_bf16.h>
#include <hip/hip_fp16.h>

#define NN 50000
#define EE 800000
#define FF 256
#define HH 256
#define CC 10
#define BB 128
#define VV 4
#define SS 16   // pooling strips per batch

typedef _Float16 half8v __attribute__((ext_vector_type(8)));
typedef float f32x4 __attribute__((ext_vector_type(4)));

// fp16 pack/unpack helpers (accumulate fp32, store fp16)
__device__ inline float2 h2f(unsigned int u) {
  __half2 h = *reinterpret_cast<__half2*>(&u);
  return __half22float2(h);
}
__device__ inline unsigned int f2h(float a, float b) {
  __half2 h = __floats2half2_rn(a, b);
  return *reinterpret_cast<unsigned int*>(&h);
}

// ---------------- degree count (by row) ----------------
__global__ __launch_bounds__(256) void k_deg(const int* __restrict__ row, int* __restrict__ deg) {
  int i = blockIdx.x * 256 + threadIdx.x;
  if (i < EE) atomicAdd(&deg[row[i]], 1);
}

// ---------------- exclusive scan -> row_ptr ----------------
__global__ __launch_bounds__(256) void k_scan(const int* __restrict__ deg, int* __restrict__ rptr) {
  __shared__ int sums[256];
  int tid = threadIdx.x;
  const int chunk = (NN + 255) / 256;
  int st = tid * chunk;
  int en = st + chunk; if (en > NN) en = NN;
  int s = 0;
  for (int i = st; i < en; ++i) s += deg[i];
  sums[tid] = s;
  __syncthreads();
  if (tid == 0) {
    int run = 0;
    for (int i = 0; i < 256; ++i) { int t = sums[i]; sums[i] = run; run += t; }
  }
  __syncthreads();
  int run = sums[tid];
  for (int i = st; i < en; ++i) { rptr[i] = run; run += deg[i]; }
  if (tid == 255) rptr[NN] = run;
}

// ---------------- scatter edges into CSR ----------------
__global__ __launch_bounds__(256) void k_scatter(const int* __restrict__ row,
                                                 const int* __restrict__ col,
                                                 const int* __restrict__ rptr,
                                                 int* __restrict__ fill,
                                                 int* __restrict__ csort) {
  int i = blockIdx.x * 256 + threadIdx.x;
  if (i < EE) {
    int r = row[i];
    int p = rptr[r] + atomicAdd(&fill[r], 1);
    csort[p] = col[i];
  }
}

// ---------------- batch_ptr via binary search (batch sorted) ----------------
__global__ __launch_bounds__(256) void k_bptr(const int* __restrict__ batch, int* __restrict__ bptr) {
  int b = threadIdx.x;
  if (b > BB) return;
  int lo = 0, hi = NN;
  while (lo < hi) { int mid = (lo + hi) >> 1; if (batch[mid] < b) lo = mid + 1; else hi = mid; }
  bptr[b] = lo;
}

// ---------------- pack 4 mask planes into float4 AoS ----------------
__global__ __launch_bounds__(256) void k_packm(const float* __restrict__ nmask, float4* __restrict__ m4) {
  int i = blockIdx.x * 256 + threadIdx.x;
  if (i < NN)
    m4[i] = make_float4(nmask[i], nmask[NN + i], nmask[2 * NN + i], nmask[3 * NN + i]);
}

// ---------------- pack W1 into MFMA B-fragment order (fp16) ----------------
// wf[((ks*16 + t)*64 + lane)*8 + j] = W[ks*32 + (lane>>4)*8 + j][t*16 + (lane&15)]
__global__ __launch_bounds__(256) void k_wfrag(const float* __restrict__ W, _Float16* __restrict__ wf) {
  int id = blockIdx.x * 256 + threadIdx.x;  // 8*16*64 = 8192 frag-lanes
  if (id >= 8 * 16 * 64) return;
  int lane = id & 63;
  int t = (id >> 6) & 15;
  int ks = id >> 10;
  int n = t * 16 + (lane & 15);
  int k0 = ks * 32 + (lane >> 4) * 8;
  half8v v;
#pragma unroll
  for (int j = 0; j < 8; ++j) v[j] = (_Float16)W[(size_t)(k0 + j) * HH + n];
  reinterpret_cast<half8v*>(wf)[id] = v;
}

// ---------------- Y = (X .* DM) @ W1 -> fp16 via MFMA, no LDS ----------------
__global__ __launch_bounds__(256) void k_gemm(const float* __restrict__ X,
                                              const float* __restrict__ DM,
                                              const _Float16* __restrict__ wf,
                                              __half* __restrict__ Z) {
  int w = threadIdx.x >> 6, lane = threadIdx.x & 63;
  int arow = blockIdx.x * 64 + w * 16 + (lane & 15);
  bool valid = arow < NN;
  const half8v* wfv = reinterpret_cast<const half8v*>(wf);
  f32x4 acc[16];
#pragma unroll
  for (int t = 0; t < 16; ++t) acc[t] = (f32x4){0.f, 0.f, 0.f, 0.f};
  for (int ks = 0; ks < 8; ++ks) {
    int k0 = ks * 32 + (lane >> 4) * 8;
    half8v a;
    if (valid) {
      const float4* xp = reinterpret_cast<const float4*>(X + (size_t)arow * FF + k0);
      const float4* dp = reinterpret_cast<const float4*>(DM + (size_t)arow * FF + k0);
      float4 x0 = xp[0], x1 = xp[1], d0 = dp[0], d1 = dp[1];
      a[0] = (_Float16)(x0.x * d0.x); a[1] = (_Float16)(x0.y * d0.y);
      a[2] = (_Float16)(x0.z * d0.z); a[3] = (_Float16)(x0.w * d0.w);
      a[4] = (_Float16)(x1.x * d1.x); a[5] = (_Float16)(x1.y * d1.y);
      a[6] = (_Float16)(x1.z * d1.z); a[7] = (_Float16)(x1.w * d1.w);
    } else {
#pragma unroll
      for (int j = 0; j < 8; ++j) a[j] = (_Float16)0.f;
    }
#pragma unroll
    for (int t = 0; t < 16; ++t) {
      half8v b = wfv[(size_t)(ks * 16 + t) * 64 + lane];
      acc[t] = __builtin_amdgcn_mfma_f32_16x16x32_f16(a, b, acc[t], 0, 0, 0);
    }
  }
  // C/D: row = (lane>>4)*4 + r, col = lane&15 (within 16x16 tile)
  int mrow = blockIdx.x * 64 + w * 16 + (lane >> 4) * 4;
  int ncol = lane & 15;
#pragma unroll
  for (int t = 0; t < 16; ++t) {
#pragma unroll
    for (int r = 0; r < 4; ++r) {
      int rr = mrow + r;
      if (rr < NN) Z[(size_t)rr * HH + t * 16 + ncol] = __float2half(acc[t][r]);
    }
  }
}

// ---------------- hop1 merged over 4 views (fp16 in/out, fp32 accum) ----------------
__global__ __launch_bounds__(256) void k_prop1(const __half* __restrict__ y,
                                               __half* __restrict__ h1,
                                               const int* __restrict__ rptr,
                                               const int* __restrict__ csort,
                                               const float4* __restrict__ m4) {
  int node = blockIdx.x * 4 + (threadIdx.x >> 6);
  if (node >= NN) return;
  int lane = threadIdx.x & 63;
  const uint2* in2 = reinterpret_cast<const uint2*>(y);
  int s = rptr[node], e = rptr[node + 1];
  float4 a0, a1, a2, a3;
  {
    uint2 raw = in2[(size_t)node * 64 + lane];
    float2 lo = h2f(raw.x), hi = h2f(raw.y);
    float4 m = m4[node];
    a0 = make_float4(lo.x * m.x, lo.y * m.x, hi.x * m.x, hi.y * m.x);
    a1 = make_float4(lo.x * m.y, lo.y * m.y, hi.x * m.y, hi.y * m.y);
    a2 = make_float4(lo.x * m.z, lo.y * m.z, hi.x * m.z, hi.y * m.z);
    a3 = make_float4(lo.x * m.w, lo.y * m.w, hi.x * m.w, hi.y * m.w);
  }
  int j = s;
  for (; j + 1 < e; j += 2) {
    int c0 = csort[j], c1 = csort[j + 1];
    uint2 r0 = in2[(size_t)c0 * 64 + lane];
    uint2 r1 = in2[(size_t)c1 * 64 + lane];
    float2 l0 = h2f(r0.x), u0 = h2f(r0.y);
    float2 l1 = h2f(r1.x), u1 = h2f(r1.y);
    float4 p = m4[c0];
    float4 q = m4[c1];
    a0.x += l0.x * p.x + l1.x * q.x; a0.y += l0.y * p.x + l1.y * q.x;
    a0.z += u0.x * p.x + u1.x * q.x; a0.w += u0.y * p.x + u1.y * q.x;
    a1.x += l0.x * p.y + l1.x * q.y; a1.y += l0.y * p.y + l1.y * q.y;
    a1.z += u0.x * p.y + u1.x * q.y; a1.w += u0.y * p.y + u1.y * q.y;
    a2.x += l0.x * p.z + l1.x * q.z; a2.y += l0.y * p.z + l1.y * q.z;
    a2.z += u0.x * p.z + u1.x * q.z; a2.w += u0.y * p.z + u1.y * q.z;
    a3.x += l0.x * p.w + l1.x * q.w; a3.y += l0.y * p.w + l1.y * q.w;
    a3.z += u0.x * p.w + u1.x * q.w; a3.w += u0.y * p.w + u1.y * q.w;
  }
  if (j < e) {
    int c0 = csort[j];
    uint2 r0 = in2[(size_t)c0 * 64 + lane];
    float2 l0 = h2f(r0.x), u0 = h2f(r0.y);
    float4 p = m4[c0];
    a0.x += l0.x * p.x; a0.y += l0.y * p.x; a0.z += u0.x * p.x; a0.w += u0.y * p.x;
    a1.x += l0.x * p.y; a1.y += l0.y * p.y; a1.z += u0.x * p.y; a1.w += u0.y * p.y;
    a2.x += l0.x * p.z; a2.y += l0.y * p.z; a2.z += u0.x * p.z; a2.w += u0.y * p.z;
    a3.x += l0.x * p.w; a3.y += l0.y * p.w; a3.z += u0.x * p.w; a3.w += u0.y * p.w;
  }
  float sc = 1.0f / (float)(e - s + 1);
  uint2* o = reinterpret_cast<uint2*>(h1);
  size_t base = (size_t)node * 64 + lane;
  o[base] = make_uint2(f2h(a0.x * sc, a0.y * sc), f2h(a0.z * sc, a0.w * sc));
  o[(size_t)NN * 64 + base] = make_uint2(f2h(a1.x * sc, a1.y * sc), f2h(a1.z * sc, a1.w * sc));
  o[(size_t)2 * NN * 64 + base] = make_uint2(f2h(a2.x * sc, a2.y * sc), f2h(a2.z * sc, a2.w * sc));
  o[(size_t)3 * NN * 64 + base] = make_uint2(f2h(a3.x * sc, a3.y * sc), f2h(a3.z * sc, a3.w * sc));
}

// ---------------- propagation hop (fp16 in/out, fp32 accum) ----------------
__global__ __launch_bounds__(256) void k_prop(const __half* __restrict__ in,
                                              __half* __restrict__ out,
                                              const int* __restrict__ rptr,
                                              const int* __restrict__ csort) {
  int node = blockIdx.x * 4 + (threadIdx.x >> 6);
  if (node >= NN) return;
  int lane = threadIdx.x & 63;
  const uint2* in2 = reinterpret_cast<const uint2*>(in);
  int s = rptr[node], e = rptr[node + 1];
  float4 acc;
  {
    uint2 raw = in2[(size_t)node * 64 + lane];
    float2 lo = h2f(raw.x), hi = h2f(raw.y);
    acc = make_float4(lo.x, lo.y, hi.x, hi.y);
  }
  int j = s;
  for (; j + 3 < e; j += 4) {
    int c0 = csort[j], c1 = csort[j + 1], c2 = csort[j + 2], c3 = csort[j + 3];
    uint2 r0 = in2[(size_t)c0 * 64 + lane];
    uint2 r1 = in2[(size_t)c1 * 64 + lane];
    uint2 r2 = in2[(size_t)c2 * 64 + lane];
    uint2 r3 = in2[(size_t)c3 * 64 + lane];
    float2 l0 = h2f(r0.x), u0 = h2f(r0.y);
    float2 l1 = h2f(r1.x), u1 = h2f(r1.y);
    float2 l2 = h2f(r2.x), u2 = h2f(r2.y);
    float2 l3 = h2f(r3.x), u3 = h2f(r3.y);
    acc.x += l0.x + l1.x + l2.x + l3.x;
    acc.y += l0.y + l1.y + l2.y + l3.y;
    acc.z += u0.x + u1.x + u2.x + u3.x;
    acc.w += u0.y + u1.y + u2.y + u3.y;
  }
  for (; j < e; ++j) {
    int c0 = csort[j];
    uint2 r0 = in2[(size_t)c0 * 64 + lane];
    float2 l0 = h2f(r0.x), u0 = h2f(r0.y);
    acc.x += l0.x; acc.y += l0.y; acc.z += u0.x; acc.w += u0.y;
  }
  float sc = 1.0f / (float)(e - s + 1);
  reinterpret_cast<uint2*>(out)[(size_t)node * 64 + lane] =
      make_uint2(f2h(acc.x * sc, acc.y * sc), f2h(acc.z * sc, acc.w * sc));
}

// ---------------- fused hop3 + bias + relu + pool (atomic into part strips) ----------------
__global__ __launch_bounds__(256) void k_prop3(const __half* __restrict__ in,
                                               const int* __restrict__ rptr,
                                               const int* __restrict__ csort,
                                               const int* __restrict__ batch,
                                               const float* __restrict__ b1,
                                               float* __restrict__ part) {
  int w = threadIdx.x >> 6, lane = threadIdx.x & 63;
  int node = blockIdx.x * 4 + w;
  __shared__ float red[4][HH];
  __shared__ int bb[4];
  const uint2* in2 = reinterpret_cast<const uint2*>(in);
  int s = rptr[node], e = rptr[node + 1];
  float4 acc;
  {
    uint2 raw = in2[(size_t)node * 64 + lane];
    float2 lo = h2f(raw.x), hi = h2f(raw.y);
    acc = make_float4(lo.x, lo.y, hi.x, hi.y);
  }
  int j = s;
  for (; j + 3 < e; j += 4) {
    int c0 = csort[j], c1 = csort[j + 1], c2 = csort[j + 2], c3 = csort[j + 3];
    uint2 r0 = in2[(size_t)c0 * 64 + lane];
    uint2 r1 = in2[(size_t)c1 * 64 + lane];
    uint2 r2 = in2[(size_t)c2 * 64 + lane];
    uint2 r3 = in2[(size_t)c3 * 64 + lane];
    float2 l0 = h2f(r0.x), u0 = h2f(r0.y);
    float2 l1 = h2f(r1.x), u1 = h2f(r1.y);
    float2 l2 = h2f(r2.x), u2 = h2f(r2.y);
    float2 l3 = h2f(r3.x), u3 = h2f(r3.y);
    acc.x += l0.x + l1.x + l2.x + l3.x;
    acc.y += l0.y + l1.y + l2.y + l3.y;
    acc.z += u0.x + u1.x + u2.x + u3.x;
    acc.w += u0.y + u1.y + u2.y + u3.y;
  }
  for (; j < e; ++j) {
    int c0 = csort[j];
    uint2 r0 = in2[(size_t)c0 * 64 + lane];
    float2 l0 = h2f(r0.x), u0 = h2f(r0.y);
    acc.x += l0.x; acc.y += l0.y; acc.z += u0.x; acc.w += u0.y;
  }
  float sc = 1.0f / (float)(e - s + 1);
  float4 bv = *reinterpret_cast<const float4*>(&b1[lane * 4]);
  red[w][lane * 4 + 0] = fmaxf(acc.x * sc + bv.x, 0.f);
  red[w][lane * 4 + 1] = fmaxf(acc.y * sc + bv.y, 0.f);
  red[w][lane * 4 + 2] = fmaxf(acc.z * sc + bv.z, 0.f);
  red[w][lane * 4 + 3] = fmaxf(acc.w * sc + bv.w, 0.f);
  if (lane == 0) bb[w] = batch[node];
  __syncthreads();
  int strip = blockIdx.x & (SS - 1);
  if (bb[0] == bb[1] && bb[1] == bb[2] && bb[2] == bb[3]) {
    int col = threadIdx.x;
    float sum = red[0][col] + red[1][col] + red[2][col] + red[3][col];
    atomicAdd(&part[((size_t)strip * BB + bb[0]) * HH + col], sum);
  } else {
    int b = bb[w];
#pragma unroll
    for (int k = 0; k < 4; ++k)
      atomicAdd(&part[((size_t)strip * BB + b) * HH + lane * 4 + k], red[w][lane * 4 + k]);
  }
}

// ---------------- head: meanpool -> @W2+b2 -> @Wc+bc -> softmax ----------------
__global__ __launch_bounds__(256) void k_head(const float* __restrict__ part,
                                              const int* __restrict__ bptr,
                                              const float* __restrict__ W2,
                                              const float* __restrict__ b2,
                                              const float* __restrict__ Wc,
                                              const float* __restrict__ bc,
                                              float* __restrict__ probs,
                                              float* __restrict__ logits) {
  int v = blockIdx.x / BB;
  int b = blockIdx.x % BB;
  int h = threadIdx.x;
  __shared__ float mr[HH];
  __shared__ float vr[HH];
  __shared__ float scs[CC];
  float acc = 0.f;
  for (int s = 0; s < SS; ++s)
    acc += part[(((size_t)v * SS + s) * BB + b) * HH + h];
  int cnt = bptr[b + 1] - bptr[b]; if (cnt < 1) cnt = 1;
  mr[h] = acc / (float)cnt;
  __syncthreads();
  float a = b2[h];
  for (int k = 0; k < HH; ++k) a += mr[k] * W2[k * HH + h];
  vr[h] = a;
  __syncthreads();
  if (h < CC) {
    float t = bc[h];
    for (int k = 0; k < HH; ++k) t += vr[k] * Wc[k * CC + h];
    scs[h] = t;
  }
  __syncthreads();
  if (h < CC) {
    float m = scs[0];
    for (int c = 1; c < CC; ++c) m = fmaxf(m, scs[c]);
    float den = 0.f;
    for (int c = 0; c < CC; ++c) den += expf(scs[c] - m);
    float p = expf(scs[h] - m) / den;
    probs[((size_t)v * BB + b) * CC + h] = p;
    if (v == 0) logits[b * CC + h] = scs[h];
  }
}

// ---------------- loss: consistency + entropy ----------------
__global__ __launch_bounds__(256) void k_loss(const float* __restrict__ probs, float* __restrict__ out) {
  __shared__ float mp[BB * CC];
  __shared__ float red[8];
  int tid = threadIdx.x;
  float ent = 0.f;
  for (int i = tid; i < BB * CC; i += 256) {
    float m = 0.25f * (probs[i] + probs[BB * CC + i] + probs[2 * BB * CC + i] + probs[3 * BB * CC + i]);
    mp[i] = m;
    ent += m * logf(m + 1e-8f);
  }
  __syncthreads();
  float cons = 0.f;
  for (int i = tid; i < VV * BB * CC; i += 256) {
    float d = probs[i] - mp[i % (BB * CC)];
    cons += d * d;
  }
  for (int o = 32; o > 0; o >>= 1) {
    cons += __shfl_down(cons, o, 64);
    ent += __shfl_down(ent, o, 64);
  }
  int wid = tid >> 6, lane = tid & 63;
  if (lane == 0) { red[wid] = cons; red[4 + wid] = ent; }
  __syncthreads();
  if (tid == 0) {
    float c = red[0] + red[1] + red[2] + red[3];
    float e2 = red[4] + red[5] + red[6] + red[7];
    out[0] = c / (float)(VV * BB) - e2 / (float)BB;
  }
}

extern "C" void kernel_launch(void* const* d_in, const int* in_sizes, int n_in,
                              void* d_out, int out_size, void* d_ws, size_t ws_size,
                              hipStream_t stream) {
  const float* x     = (const float*)d_in[0];
  const int*   erow  = (const int*)d_in[1];          // edge_index[0]
  const int*   ecol  = ((const int*)d_in[1]) + EE;   // edge_index[1]
  const int*   batch = (const int*)d_in[2];
  const float* dm    = (const float*)d_in[3];
  const float* nmask = (const float*)d_in[4];
  const float* W1    = (const float*)d_in[5];
  const float* b1    = (const float*)d_in[6];
  const float* W2    = (const float*)d_in[7];
  const float* b2    = (const float*)d_in[8];
  const float* Wc    = (const float*)d_in[9];
  const float* bc    = (const float*)d_in[10];
  float* out = (float*)d_out;

  char* ws = (char*)d_ws;
  size_t off = 0;
  auto carve = [&](size_t bytes) -> char* {
    char* p = ws + off;
    off = (off + bytes + 255) & ~(size_t)255;
    return p;
  };
  float* part  = (float*)carve((size_t)VV * SS * BB * HH * 4);
  int*   deg   = (int*)carve((size_t)NN * 4);
  int*   fill  = (int*)carve((size_t)NN * 4);
  int*   rptr  = (int*)carve((size_t)(NN + 1) * 4);
  int*   csort = (int*)carve((size_t)EE * 4);
  int*   bptr  = (int*)carve((size_t)(BB + 1) * 4);
  float* probs = (float*)carve((size_t)VV * BB * CC * 4);
  float4* m4   = (float4*)carve((size_t)NN * 16);
  _Float16* wf = (_Float16*)carve((size_t)8 * 16 * 64 * 8 * 2);  // 128 KB

  const size_t NFh = (size_t)NN * FF * 2;  // 25.6 MB fp16 node-feature plane
  __half* y  = (__half*)carve(NFh);        // GEMM out; reused as hop2 temp
  __half* h1 = (__half*)carve(NFh * VV);

  hipMemsetAsync(deg, 0, (size_t)NN * 4, stream);
  hipMemsetAsync(fill, 0, (size_t)NN * 4, stream);
  hipMemsetAsync(part, 0, (size_t)VV * SS * BB * HH * 4, stream);

  k_deg<<<(EE + 255) / 256, 256, 0, stream>>>(erow, deg);
  k_scan<<<1, 256, 0, stream>>>(deg, rptr);
  k_scatter<<<(EE + 255) / 256, 256, 0, stream>>>(erow, ecol, rptr, fill, csort);
  k_bptr<<<1, 256, 0, stream>>>(batch, bptr);
  k_packm<<<(NN + 255) / 256, 256, 0, stream>>>(nmask, m4);
  k_wfrag<<<32, 256, 0, stream>>>(W1, wf);

  k_gemm<<<(NN + 63) / 64, 256, 0, stream>>>(x, dm, wf, y);
  k_prop1<<<(NN + 3) / 4, 256, 0, stream>>>(y, h1, rptr, csort, m4);
  for (int v = 0; v < VV; ++v) {
    __half* hv = h1 + (size_t)v * NN * FF;
    k_prop<<<(NN + 3) / 4, 256, 0, stream>>>(hv, y, rptr, csort);          // hop2 -> y (reused)
    k_prop3<<<(NN + 3) / 4, 256, 0, stream>>>(y, rptr, csort, batch, b1,
                                              part + (size_t)v * SS * BB * HH);  // hop3+relu+pool
  }
  k_head<<<VV * BB, 256, 0, stream>>>(part, bptr, W2, b2, Wc, bc, probs, out);
  k_loss<<<1, 256, 0, stream>>>(probs, out + BB * CC);
}

// Round 6
// 789.832 us; speedup vs baseline: 2.8049x; 1.1959x over previous
//
#include <hip/hip_runtime.h>
#include <hip/hip_bf16.h>
#include <hip/hip_fp16.h>

#define NN 50000
#define EE 800000
#define FF 256
#define HH 256
#define CC 10
#define BB 128
#define VV 4
#define SS 16    // pooling strips per batch
#define NBLK 196 // ceil(NN/256)

typedef _Float16 half8v __attribute__((ext_vector_type(8)));
typedef float f32x4 __attribute__((ext_vector_type(4)));

// fp16 pack/unpack helpers (accumulate fp32, store fp16)
__device__ inline float2 h2f(unsigned int u) {
  __half2 h = *reinterpret_cast<__half2*>(&u);
  return __half22float2(h);
}
__device__ inline unsigned int f2h(float a, float b) {
  __half2 h = __floats2half2_rn(a, b);
  return *reinterpret_cast<unsigned int*>(&h);
}
// fp8 (OCP e4m3 on gfx950) pack/unpack: 4 values per uint
__device__ inline void fp8x4_to_f32(unsigned int u, float* f) {
  auto lo = __builtin_amdgcn_cvt_pk_f32_fp8(u, false);
  auto hi = __builtin_amdgcn_cvt_pk_f32_fp8(u, true);
  f[0] = lo[0]; f[1] = lo[1]; f[2] = hi[0]; f[3] = hi[1];
}
__device__ inline unsigned int f32x4_to_fp8(float a, float b, float c, float d) {
  int u = __builtin_amdgcn_cvt_pk_fp8_f32(a, b, 0, false);
  u = __builtin_amdgcn_cvt_pk_fp8_f32(c, d, u, true);
  return (unsigned int)u;
}

// ---------------- degree count (by row) ----------------
__global__ __launch_bounds__(256) void k_deg(const int* __restrict__ row, int* __restrict__ deg) {
  int i = blockIdx.x * 256 + threadIdx.x;
  if (i < EE) atomicAdd(&deg[row[i]], 1);
}

// ---------------- parallel scan: stage 1 block sums ----------------
__global__ __launch_bounds__(256) void k_scan1(const int* __restrict__ deg, int* __restrict__ bsum) {
  int i = blockIdx.x * 256 + threadIdx.x;
  int v = (i < NN) ? deg[i] : 0;
  for (int o = 32; o > 0; o >>= 1) v += __shfl_down(v, o, 64);
  __shared__ int ws[4];
  if ((threadIdx.x & 63) == 0) ws[threadIdx.x >> 6] = v;
  __syncthreads();
  if (threadIdx.x == 0) bsum[blockIdx.x] = ws[0] + ws[1] + ws[2] + ws[3];
}

// ---------------- parallel scan: stage 2 exclusive scan of block sums ----------------
__global__ __launch_bounds__(256) void k_scan2(const int* __restrict__ bsum, int* __restrict__ boff) {
  __shared__ int tmp[256];
  int tid = threadIdx.x;
  int v = (tid < NBLK) ? bsum[tid] : 0;
  tmp[tid] = v;
  __syncthreads();
  for (int o = 1; o < 256; o <<= 1) {
    int t = 0;
    if (tid >= o) t = tmp[tid - o];
    __syncthreads();
    if (tid >= o) tmp[tid] += t;
    __syncthreads();
  }
  if (tid < NBLK) boff[tid] = tmp[tid] - v;
}

// ---------------- parallel scan: stage 3 per-block scan + offset -> rptr ----------------
__global__ __launch_bounds__(256) void k_scan3(const int* __restrict__ deg,
                                               const int* __restrict__ boff,
                                               int* __restrict__ rptr) {
  __shared__ int tmp[256];
  int tid = threadIdx.x;
  int i = blockIdx.x * 256 + tid;
  int v = (i < NN) ? deg[i] : 0;
  tmp[tid] = v;
  __syncthreads();
  for (int o = 1; o < 256; o <<= 1) {
    int t = 0;
    if (tid >= o) t = tmp[tid - o];
    __syncthreads();
    if (tid >= o) tmp[tid] += t;
    __syncthreads();
  }
  int incl = tmp[tid];
  if (i < NN) rptr[i] = boff[blockIdx.x] + incl - v;
  if (i == NN - 1) rptr[NN] = boff[blockIdx.x] + incl;
}

// ---------------- scatter edges into CSR ----------------
__global__ __launch_bounds__(256) void k_scatter(const int* __restrict__ row,
                                                 const int* __restrict__ col,
                                                 const int* __restrict__ rptr,
                                                 int* __restrict__ fill,
                                                 int* __restrict__ csort) {
  int i = blockIdx.x * 256 + threadIdx.x;
  if (i < EE) {
    int r = row[i];
    int p = rptr[r] + atomicAdd(&fill[r], 1);
    csort[p] = col[i];
  }
}

// ---------------- batch_ptr via binary search (batch sorted) ----------------
__global__ __launch_bounds__(256) void k_bptr(const int* __restrict__ batch, int* __restrict__ bptr) {
  int b = threadIdx.x;
  if (b > BB) return;
  int lo = 0, hi = NN;
  while (lo < hi) { int mid = (lo + hi) >> 1; if (batch[mid] < b) lo = mid + 1; else hi = mid; }
  bptr[b] = lo;
}

// ---------------- pack 4 mask planes into float4 AoS ----------------
__global__ __launch_bounds__(256) void k_packm(const float* __restrict__ nmask, float4* __restrict__ m4) {
  int i = blockIdx.x * 256 + threadIdx.x;
  if (i < NN)
    m4[i] = make_float4(nmask[i], nmask[NN + i], nmask[2 * NN + i], nmask[3 * NN + i]);
}

// ---------------- pack W1 into MFMA B-fragment order (fp16) ----------------
__global__ __launch_bounds__(256) void k_wfrag(const float* __restrict__ W, _Float16* __restrict__ wf) {
  int id = blockIdx.x * 256 + threadIdx.x;  // 8*16*64 = 8192 frag-lanes
  if (id >= 8 * 16 * 64) return;
  int lane = id & 63;
  int t = (id >> 6) & 15;
  int ks = id >> 10;
  int n = t * 16 + (lane & 15);
  int k0 = ks * 32 + (lane >> 4) * 8;
  half8v v;
#pragma unroll
  for (int j = 0; j < 8; ++j) v[j] = (_Float16)W[(size_t)(k0 + j) * HH + n];
  reinterpret_cast<half8v*>(wf)[id] = v;
}

// ---------------- Y = (X .* DM) @ W1 -> fp16 via MFMA, no LDS ----------------
__global__ __launch_bounds__(256) void k_gemm(const float* __restrict__ X,
                                              const float* __restrict__ DM,
                                              const _Float16* __restrict__ wf,
                                              __half* __restrict__ Z) {
  int w = threadIdx.x >> 6, lane = threadIdx.x & 63;
  int arow = blockIdx.x * 64 + w * 16 + (lane & 15);
  bool valid = arow < NN;
  const half8v* wfv = reinterpret_cast<const half8v*>(wf);
  f32x4 acc[16];
#pragma unroll
  for (int t = 0; t < 16; ++t) acc[t] = (f32x4){0.f, 0.f, 0.f, 0.f};
  for (int ks = 0; ks < 8; ++ks) {
    int k0 = ks * 32 + (lane >> 4) * 8;
    half8v a;
    if (valid) {
      const float4* xp = reinterpret_cast<const float4*>(X + (size_t)arow * FF + k0);
      const float4* dp = reinterpret_cast<const float4*>(DM + (size_t)arow * FF + k0);
      float4 x0 = xp[0], x1 = xp[1], d0 = dp[0], d1 = dp[1];
      a[0] = (_Float16)(x0.x * d0.x); a[1] = (_Float16)(x0.y * d0.y);
      a[2] = (_Float16)(x0.z * d0.z); a[3] = (_Float16)(x0.w * d0.w);
      a[4] = (_Float16)(x1.x * d1.x); a[5] = (_Float16)(x1.y * d1.y);
      a[6] = (_Float16)(x1.z * d1.z); a[7] = (_Float16)(x1.w * d1.w);
    } else {
#pragma unroll
      for (int j = 0; j < 8; ++j) a[j] = (_Float16)0.f;
    }
#pragma unroll
    for (int t = 0; t < 16; ++t) {
      half8v b = wfv[(size_t)(ks * 16 + t) * 64 + lane];
      acc[t] = __builtin_amdgcn_mfma_f32_16x16x32_f16(a, b, acc[t], 0, 0, 0);
    }
  }
  int mrow = blockIdx.x * 64 + w * 16 + (lane >> 4) * 4;
  int ncol = lane & 15;
#pragma unroll
  for (int t = 0; t < 16; ++t) {
#pragma unroll
    for (int r = 0; r < 4; ++r) {
      int rr = mrow + r;
      if (rr < NN) Z[(size_t)rr * HH + t * 16 + ncol] = __float2half(acc[t][r]);
    }
  }
}

// ---------------- hop1 merged over 4 views (fp16 in/out, fp32 accum) ----------------
__global__ __launch_bounds__(256) void k_prop1(const __half* __restrict__ y,
                                               __half* __restrict__ h1,
                                               const int* __restrict__ rptr,
                                               const int* __restrict__ csort,
                                               const float4* __restrict__ m4) {
  int node = blockIdx.x * 4 + (threadIdx.x >> 6);
  if (node >= NN) return;
  int lane = threadIdx.x & 63;
  const uint2* in2 = reinterpret_cast<const uint2*>(y);
  int s = rptr[node], e = rptr[node + 1];
  float4 a0, a1, a2, a3;
  {
    uint2 raw = in2[(size_t)node * 64 + lane];
    float2 lo = h2f(raw.x), hi = h2f(raw.y);
    float4 m = m4[node];
    a0 = make_float4(lo.x * m.x, lo.y * m.x, hi.x * m.x, hi.y * m.x);
    a1 = make_float4(lo.x * m.y, lo.y * m.y, hi.x * m.y, hi.y * m.y);
    a2 = make_float4(lo.x * m.z, lo.y * m.z, hi.x * m.z, hi.y * m.z);
    a3 = make_float4(lo.x * m.w, lo.y * m.w, hi.x * m.w, hi.y * m.w);
  }
  int j = s;
  for (; j + 1 < e; j += 2) {
    int c0 = csort[j], c1 = csort[j + 1];
    uint2 r0 = in2[(size_t)c0 * 64 + lane];
    uint2 r1 = in2[(size_t)c1 * 64 + lane];
    float2 l0 = h2f(r0.x), u0 = h2f(r0.y);
    float2 l1 = h2f(r1.x), u1 = h2f(r1.y);
    float4 p = m4[c0];
    float4 q = m4[c1];
    a0.x += l0.x * p.x + l1.x * q.x; a0.y += l0.y * p.x + l1.y * q.x;
    a0.z += u0.x * p.x + u1.x * q.x; a0.w += u0.y * p.x + u1.y * q.x;
    a1.x += l0.x * p.y + l1.x * q.y; a1.y += l0.y * p.y + l1.y * q.y;
    a1.z += u0.x * p.y + u1.x * q.y; a1.w += u0.y * p.y + u1.y * q.y;
    a2.x += l0.x * p.z + l1.x * q.z; a2.y += l0.y * p.z + l1.y * q.z;
    a2.z += u0.x * p.z + u1.x * q.z; a2.w += u0.y * p.z + u1.y * q.z;
    a3.x += l0.x * p.w + l1.x * q.w; a3.y += l0.y * p.w + l1.y * q.w;
    a3.z += u0.x * p.w + u1.x * q.w; a3.w += u0.y * p.w + u1.y * q.w;
  }
  if (j < e) {
    int c0 = csort[j];
    uint2 r0 = in2[(size_t)c0 * 64 + lane];
    float2 l0 = h2f(r0.x), u0 = h2f(r0.y);
    float4 p = m4[c0];
    a0.x += l0.x * p.x; a0.y += l0.y * p.x; a0.z += u0.x * p.x; a0.w += u0.y * p.x;
    a1.x += l0.x * p.y; a1.y += l0.y * p.y; a1.z += u0.x * p.y; a1.w += u0.y * p.y;
    a2.x += l0.x * p.z; a2.y += l0.y * p.z; a2.z += u0.x * p.z; a2.w += u0.y * p.z;
    a3.x += l0.x * p.w; a3.y += l0.y * p.w; a3.z += u0.x * p.w; a3.w += u0.y * p.w;
  }
  float sc = 1.0f / (float)(e - s + 1);
  uint2* o = reinterpret_cast<uint2*>(h1);
  size_t base = (size_t)node * 64 + lane;
  o[base] = make_uint2(f2h(a0.x * sc, a0.y * sc), f2h(a0.z * sc, a0.w * sc));
  o[(size_t)NN * 64 + base] = make_uint2(f2h(a1.x * sc, a1.y * sc), f2h(a1.z * sc, a1.w * sc));
  o[(size_t)2 * NN * 64 + base] = make_uint2(f2h(a2.x * sc, a2.y * sc), f2h(a2.z * sc, a2.w * sc));
  o[(size_t)3 * NN * 64 + base] = make_uint2(f2h(a3.x * sc, a3.y * sc), f2h(a3.z * sc, a3.w * sc));
}

// ---------------- hop2: fp16 in, fp8 out (fp32 accum) ----------------
__global__ __launch_bounds__(256) void k_prop2(const __half* __restrict__ in,
                                               unsigned int* __restrict__ out8,
                                               const int* __restrict__ rptr,
                                               const int* __restrict__ csort) {
  int node = blockIdx.x * 4 + (threadIdx.x >> 6);
  if (node >= NN) return;
  int lane = threadIdx.x & 63;
  const uint2* in2 = reinterpret_cast<const uint2*>(in);
  int s = rptr[node], e = rptr[node + 1];
  float4 acc;
  {
    uint2 raw = in2[(size_t)node * 64 + lane];
    float2 lo = h2f(raw.x), hi = h2f(raw.y);
    acc = make_float4(lo.x, lo.y, hi.x, hi.y);
  }
  int j = s;
  for (; j + 3 < e; j += 4) {
    int c0 = csort[j], c1 = csort[j + 1], c2 = csort[j + 2], c3 = csort[j + 3];
    uint2 r0 = in2[(size_t)c0 * 64 + lane];
    uint2 r1 = in2[(size_t)c1 * 64 + lane];
    uint2 r2 = in2[(size_t)c2 * 64 + lane];
    uint2 r3 = in2[(size_t)c3 * 64 + lane];
    float2 l0 = h2f(r0.x), u0 = h2f(r0.y);
    float2 l1 = h2f(r1.x), u1 = h2f(r1.y);
    float2 l2 = h2f(r2.x), u2 = h2f(r2.y);
    float2 l3 = h2f(r3.x), u3 = h2f(r3.y);
    acc.x += l0.x + l1.x + l2.x + l3.x;
    acc.y += l0.y + l1.y + l2.y + l3.y;
    acc.z += u0.x + u1.x + u2.x + u3.x;
    acc.w += u0.y + u1.y + u2.y + u3.y;
  }
  for (; j < e; ++j) {
    int c0 = csort[j];
    uint2 r0 = in2[(size_t)c0 * 64 + lane];
    float2 l0 = h2f(r0.x), u0 = h2f(r0.y);
    acc.x += l0.x; acc.y += l0.y; acc.z += u0.x; acc.w += u0.y;
  }
  float sc = 1.0f / (float)(e - s + 1);
  out8[(size_t)node * 64 + lane] =
      f32x4_to_fp8(acc.x * sc, acc.y * sc, acc.z * sc, acc.w * sc);
}

// ---------------- fused hop3 (fp8 in) + bias + relu + pool ----------------
__global__ __launch_bounds__(256) void k_prop3(const unsigned int* __restrict__ in8,
                                               const int* __restrict__ rptr,
                                               const int* __restrict__ csort,
                                               const int* __restrict__ batch,
                                               const float* __restrict__ b1,
                                               float* __restrict__ part) {
  int w = threadIdx.x >> 6, lane = threadIdx.x & 63;
  int node = blockIdx.x * 4 + w;
  __shared__ float red[4][HH];
  __shared__ int bb[4];
  int s = rptr[node], e = rptr[node + 1];
  float4 acc;
  {
    float f[4];
    fp8x4_to_f32(in8[(size_t)node * 64 + lane], f);
    acc = make_float4(f[0], f[1], f[2], f[3]);
  }
  int j = s;
  for (; j + 3 < e; j += 4) {
    int c0 = csort[j], c1 = csort[j + 1], c2 = csort[j + 2], c3 = csort[j + 3];
    unsigned int r0 = in8[(size_t)c0 * 64 + lane];
    unsigned int r1 = in8[(size_t)c1 * 64 + lane];
    unsigned int r2 = in8[(size_t)c2 * 64 + lane];
    unsigned int r3 = in8[(size_t)c3 * 64 + lane];
    float f0[4], f1[4], f2[4], f3[4];
    fp8x4_to_f32(r0, f0); fp8x4_to_f32(r1, f1);
    fp8x4_to_f32(r2, f2); fp8x4_to_f32(r3, f3);
    acc.x += f0[0] + f1[0] + f2[0] + f3[0];
    acc.y += f0[1] + f1[1] + f2[1] + f3[1];
    acc.z += f0[2] + f1[2] + f2[2] + f3[2];
    acc.w += f0[3] + f1[3] + f2[3] + f3[3];
  }
  for (; j < e; ++j) {
    int c0 = csort[j];
    float f[4];
    fp8x4_to_f32(in8[(size_t)c0 * 64 + lane], f);
    acc.x += f[0]; acc.y += f[1]; acc.z += f[2]; acc.w += f[3];
  }
  float sc = 1.0f / (float)(e - s + 1);
  float4 bv = *reinterpret_cast<const float4*>(&b1[lane * 4]);
  red[w][lane * 4 + 0] = fmaxf(acc.x * sc + bv.x, 0.f);
  red[w][lane * 4 + 1] = fmaxf(acc.y * sc + bv.y, 0.f);
  red[w][lane * 4 + 2] = fmaxf(acc.z * sc + bv.z, 0.f);
  red[w][lane * 4 + 3] = fmaxf(acc.w * sc + bv.w, 0.f);
  if (lane == 0) bb[w] = batch[node];
  __syncthreads();
  int strip = blockIdx.x & (SS - 1);
  if (bb[0] == bb[1] && bb[1] == bb[2] && bb[2] == bb[3]) {
    int col = threadIdx.x;
    float sum = red[0][col] + red[1][col] + red[2][col] + red[3][col];
    atomicAdd(&part[((size_t)strip * BB + bb[0]) * HH + col], sum);
  } else {
    int b = bb[w];
#pragma unroll
    for (int k = 0; k < 4; ++k)
      atomicAdd(&part[((size_t)strip * BB + b) * HH + lane * 4 + k], red[w][lane * 4 + k]);
  }
}

// ---------------- head: meanpool -> @W2+b2 -> @Wc+bc -> softmax ----------------
__global__ __launch_bounds__(256) void k_head(const float* __restrict__ part,
                                              const int* __restrict__ bptr,
                                              const float* __restrict__ W2,
                                              const float* __restrict__ b2,
                                              const float* __restrict__ Wc,
                                              const float* __restrict__ bc,
                                              float* __restrict__ probs,
                                              float* __restrict__ logits) {
  int v = blockIdx.x / BB;
  int b = blockIdx.x % BB;
  int h = threadIdx.x;
  __shared__ float mr[HH];
  __shared__ float vr[HH];
  __shared__ float scs[CC];
  float acc = 0.f;
  for (int s = 0; s < SS; ++s)
    acc += part[(((size_t)v * SS + s) * BB + b) * HH + h];
  int cnt = bptr[b + 1] - bptr[b]; if (cnt < 1) cnt = 1;
  mr[h] = acc / (float)cnt;
  __syncthreads();
  float a = b2[h];
  for (int k = 0; k < HH; ++k) a += mr[k] * W2[k * HH + h];
  vr[h] = a;
  __syncthreads();
  if (h < CC) {
    float t = bc[h];
    for (int k = 0; k < HH; ++k) t += vr[k] * Wc[k * CC + h];
    scs[h] = t;
  }
  __syncthreads();
  if (h < CC) {
    float m = scs[0];
    for (int c = 1; c < CC; ++c) m = fmaxf(m, scs[c]);
    float den = 0.f;
    for (int c = 0; c < CC; ++c) den += expf(scs[c] - m);
    float p = expf(scs[h] - m) / den;
    probs[((size_t)v * BB + b) * CC + h] = p;
    if (v == 0) logits[b * CC + h] = scs[h];
  }
}

// ---------------- loss: consistency + entropy ----------------
__global__ __launch_bounds__(256) void k_loss(const float* __restrict__ probs, float* __restrict__ out) {
  __shared__ float mp[BB * CC];
  __shared__ float red[8];
  int tid = threadIdx.x;
  float ent = 0.f;
  for (int i = tid; i < BB * CC; i += 256) {
    float m = 0.25f * (probs[i] + probs[BB * CC + i] + probs[2 * BB * CC + i] + probs[3 * BB * CC + i]);
    mp[i] = m;
    ent += m * logf(m + 1e-8f);
  }
  __syncthreads();
  float cons = 0.f;
  for (int i = tid; i < VV * BB * CC; i += 256) {
    float d = probs[i] - mp[i % (BB * CC)];
    cons += d * d;
  }
  for (int o = 32; o > 0; o >>= 1) {
    cons += __shfl_down(cons, o, 64);
    ent += __shfl_down(ent, o, 64);
  }
  int wid = tid >> 6, lane = tid & 63;
  if (lane == 0) { red[wid] = cons; red[4 + wid] = ent; }
  __syncthreads();
  if (tid == 0) {
    float c = red[0] + red[1] + red[2] + red[3];
    float e2 = red[4] + red[5] + red[6] + red[7];
    out[0] = c / (float)(VV * BB) - e2 / (float)BB;
  }
}

extern "C" void kernel_launch(void* const* d_in, const int* in_sizes, int n_in,
                              void* d_out, int out_size, void* d_ws, size_t ws_size,
                              hipStream_t stream) {
  const float* x     = (const float*)d_in[0];
  const int*   erow  = (const int*)d_in[1];          // edge_index[0]
  const int*   ecol  = ((const int*)d_in[1]) + EE;   // edge_index[1]
  const int*   batch = (const int*)d_in[2];
  const float* dm    = (const float*)d_in[3];
  const float* nmask = (const float*)d_in[4];
  const float* W1    = (const float*)d_in[5];
  const float* b1    = (const float*)d_in[6];
  const float* W2    = (const float*)d_in[7];
  const float* b2    = (const float*)d_in[8];
  const float* Wc    = (const float*)d_in[9];
  const float* bc    = (const float*)d_in[10];
  float* out = (float*)d_out;

  char* ws = (char*)d_ws;
  size_t off = 0;
  auto carve = [&](size_t bytes) -> char* {
    char* p = ws + off;
    off = (off + bytes + 255) & ~(size_t)255;
    return p;
  };
  float* part  = (float*)carve((size_t)VV * SS * BB * HH * 4);
  int*   deg   = (int*)carve((size_t)NN * 4);
  int*   fill  = (int*)carve((size_t)NN * 4);
  int*   rptr  = (int*)carve((size_t)(NN + 1) * 4);
  int*   csort = (int*)carve((size_t)EE * 4);
  int*   bptr  = (int*)carve((size_t)(BB + 1) * 4);
  int*   bsum  = (int*)carve(256 * 4);
  int*   boff  = (int*)carve(256 * 4);
  float* probs = (float*)carve((size_t)VV * BB * CC * 4);
  float4* m4   = (float4*)carve((size_t)NN * 16);
  _Float16* wf = (_Float16*)carve((size_t)8 * 16 * 64 * 8 * 2);  // 128 KB

  const size_t NFh = (size_t)NN * FF * 2;  // 25.6 MB fp16 node-feature plane
  __half* y  = (__half*)carve(NFh);        // GEMM out
  __half* h1 = (__half*)carve(NFh * VV);   // 4 view planes (fp16)
  unsigned int* q8 = (unsigned int*)carve((size_t)NN * 256);  // 12.8 MB fp8 plane

  hipMemsetAsync(deg, 0, (size_t)NN * 4, stream);
  hipMemsetAsync(fill, 0, (size_t)NN * 4, stream);
  hipMemsetAsync(part, 0, (size_t)VV * SS * BB * HH * 4, stream);

  k_deg<<<(EE + 255) / 256, 256, 0, stream>>>(erow, deg);
  k_scan1<<<NBLK, 256, 0, stream>>>(deg, bsum);
  k_scan2<<<1, 256, 0, stream>>>(bsum, boff);
  k_scan3<<<NBLK, 256, 0, stream>>>(deg, boff, rptr);
  k_scatter<<<(EE + 255) / 256, 256, 0, stream>>>(erow, ecol, rptr, fill, csort);
  k_bptr<<<1, 256, 0, stream>>>(batch, bptr);
  k_packm<<<(NN + 255) / 256, 256, 0, stream>>>(nmask, m4);
  k_wfrag<<<32, 256, 0, stream>>>(W1, wf);

  k_gemm<<<(NN + 63) / 64, 256, 0, stream>>>(x, dm, wf, y);
  k_prop1<<<(NN + 3) / 4, 256, 0, stream>>>(y, h1, rptr, csort, m4);
  for (int v = 0; v < VV; ++v) {
    __half* hv = h1 + (size_t)v * NN * FF;
    k_prop2<<<(NN + 3) / 4, 256, 0, stream>>>(hv, q8, rptr, csort);        // hop2 -> fp8
    k_prop3<<<(NN + 3) / 4, 256, 0, stream>>>(q8, rptr, csort, batch, b1,
                                              part + (size_t)v * SS * BB * HH);  // hop3+relu+pool
  }
  k_head<<<VV * BB, 256, 0, stream>>>(part, bptr, W2, b2, Wc, bc, probs, out);
  k_loss<<<1, 256, 0, stream>>>(probs, out + BB * CC);
}

// Round 7
// 623.133 us; speedup vs baseline: 3.5553x; 1.2675x over previous
//
#include <hip/hip_runtime.h>
#include <hip/hip_bf16.h>
#include <hip/hip_fp16.h>

#define NN 50000
#define EE 800000
#define FF 256
#define HH 256
#define CC 10
#define BB 128
#define VV 4
#define SS 16    // pooling strips per batch
#define NBLK 196 // ceil(NN/256)

typedef _Float16 half8v __attribute__((ext_vector_type(8)));
typedef float f32x4 __attribute__((ext_vector_type(4)));

// fp16 pack/unpack helpers
__device__ inline float2 h2f(unsigned int u) {
  __half2 h = *reinterpret_cast<__half2*>(&u);
  return __half22float2(h);
}
__device__ inline unsigned int f2h(float a, float b) {
  __half2 h = __floats2half2_rn(a, b);
  return *reinterpret_cast<unsigned int*>(&h);
}
// fp8 (OCP e4m3 on gfx950) pack/unpack: 4 values per uint
__device__ inline void fp8x4_to_f32(unsigned int u, float* f) {
  auto lo = __builtin_amdgcn_cvt_pk_f32_fp8(u, false);
  auto hi = __builtin_amdgcn_cvt_pk_f32_fp8(u, true);
  f[0] = lo[0]; f[1] = lo[1]; f[2] = hi[0]; f[3] = hi[1];
}
__device__ inline unsigned int f32x4_to_fp8(float a, float b, float c, float d) {
  int u = __builtin_amdgcn_cvt_pk_fp8_f32(a, b, 0, false);
  u = __builtin_amdgcn_cvt_pk_fp8_f32(c, d, u, true);
  return (unsigned int)u;
}

// ---------------- degree count (by row) ----------------
__global__ __launch_bounds__(256) void k_deg(const int* __restrict__ row, int* __restrict__ deg) {
  int i = blockIdx.x * 256 + threadIdx.x;
  if (i < EE) atomicAdd(&deg[row[i]], 1);
}

// ---------------- parallel scan: stage 1 block sums ----------------
__global__ __launch_bounds__(256) void k_scan1(const int* __restrict__ deg, int* __restrict__ bsum) {
  int i = blockIdx.x * 256 + threadIdx.x;
  int v = (i < NN) ? deg[i] : 0;
  for (int o = 32; o > 0; o >>= 1) v += __shfl_down(v, o, 64);
  __shared__ int ws[4];
  if ((threadIdx.x & 63) == 0) ws[threadIdx.x >> 6] = v;
  __syncthreads();
  if (threadIdx.x == 0) bsum[blockIdx.x] = ws[0] + ws[1] + ws[2] + ws[3];
}

// ---------------- parallel scan: stage 2 exclusive scan of block sums ----------------
__global__ __launch_bounds__(256) void k_scan2(const int* __restrict__ bsum, int* __restrict__ boff) {
  __shared__ int tmp[256];
  int tid = threadIdx.x;
  int v = (tid < NBLK) ? bsum[tid] : 0;
  tmp[tid] = v;
  __syncthreads();
  for (int o = 1; o < 256; o <<= 1) {
    int t = 0;
    if (tid >= o) t = tmp[tid - o];
    __syncthreads();
    if (tid >= o) tmp[tid] += t;
    __syncthreads();
  }
  if (tid < NBLK) boff[tid] = tmp[tid] - v;
}

// ---------------- parallel scan: stage 3 per-block scan + offset -> rptr ----------------
__global__ __launch_bounds__(256) void k_scan3(const int* __restrict__ deg,
                                               const int* __restrict__ boff,
                                               int* __restrict__ rptr) {
  __shared__ int tmp[256];
  int tid = threadIdx.x;
  int i = blockIdx.x * 256 + tid;
  int v = (i < NN) ? deg[i] : 0;
  tmp[tid] = v;
  __syncthreads();
  for (int o = 1; o < 256; o <<= 1) {
    int t = 0;
    if (tid >= o) t = tmp[tid - o];
    __syncthreads();
    if (tid >= o) tmp[tid] += t;
    __syncthreads();
  }
  int incl = tmp[tid];
  if (i < NN) rptr[i] = boff[blockIdx.x] + incl - v;
  if (i == NN - 1) rptr[NN] = boff[blockIdx.x] + incl;
}

// ---------------- scatter edges into CSR ----------------
__global__ __launch_bounds__(256) void k_scatter(const int* __restrict__ row,
                                                 const int* __restrict__ col,
                                                 const int* __restrict__ rptr,
                                                 int* __restrict__ fill,
                                                 int* __restrict__ csort) {
  int i = blockIdx.x * 256 + threadIdx.x;
  if (i < EE) {
    int r = row[i];
    int p = rptr[r] + atomicAdd(&fill[r], 1);
    csort[p] = col[i];
  }
}

// ---------------- batch_ptr via binary search (batch sorted) ----------------
__global__ __launch_bounds__(256) void k_bptr(const int* __restrict__ batch, int* __restrict__ bptr) {
  int b = threadIdx.x;
  if (b > BB) return;
  int lo = 0, hi = NN;
  while (lo < hi) { int mid = (lo + hi) >> 1; if (batch[mid] < b) lo = mid + 1; else hi = mid; }
  bptr[b] = lo;
}

// ---------------- pack 4 mask planes into float4 AoS ----------------
__global__ __launch_bounds__(256) void k_packm(const float* __restrict__ nmask, float4* __restrict__ m4) {
  int i = blockIdx.x * 256 + threadIdx.x;
  if (i < NN)
    m4[i] = make_float4(nmask[i], nmask[NN + i], nmask[2 * NN + i], nmask[3 * NN + i]);
}

// ---------------- pack W1 into MFMA B-fragment order (fp16) ----------------
__global__ __launch_bounds__(256) void k_wfrag(const float* __restrict__ W, _Float16* __restrict__ wf) {
  int id = blockIdx.x * 256 + threadIdx.x;  // 8*16*64 = 8192 frag-lanes
  if (id >= 8 * 16 * 64) return;
  int lane = id & 63;
  int t = (id >> 6) & 15;
  int ks = id >> 10;
  int n = t * 16 + (lane & 15);
  int k0 = ks * 32 + (lane >> 4) * 8;
  half8v v;
#pragma unroll
  for (int j = 0; j < 8; ++j) v[j] = (_Float16)W[(size_t)(k0 + j) * HH + n];
  reinterpret_cast<half8v*>(wf)[id] = v;
}

// ---------------- Y = (X .* DM) @ W1 -> fp16 via MFMA, no LDS ----------------
__global__ __launch_bounds__(256) void k_gemm(const float* __restrict__ X,
                                              const float* __restrict__ DM,
                                              const _Float16* __restrict__ wf,
                                              __half* __restrict__ Z) {
  int w = threadIdx.x >> 6, lane = threadIdx.x & 63;
  int arow = blockIdx.x * 64 + w * 16 + (lane & 15);
  bool valid = arow < NN;
  const half8v* wfv = reinterpret_cast<const half8v*>(wf);
  f32x4 acc[16];
#pragma unroll
  for (int t = 0; t < 16; ++t) acc[t] = (f32x4){0.f, 0.f, 0.f, 0.f};
  for (int ks = 0; ks < 8; ++ks) {
    int k0 = ks * 32 + (lane >> 4) * 8;
    half8v a;
    if (valid) {
      const float4* xp = reinterpret_cast<const float4*>(X + (size_t)arow * FF + k0);
      const float4* dp = reinterpret_cast<const float4*>(DM + (size_t)arow * FF + k0);
      float4 x0 = xp[0], x1 = xp[1], d0 = dp[0], d1 = dp[1];
      a[0] = (_Float16)(x0.x * d0.x); a[1] = (_Float16)(x0.y * d0.y);
      a[2] = (_Float16)(x0.z * d0.z); a[3] = (_Float16)(x0.w * d0.w);
      a[4] = (_Float16)(x1.x * d1.x); a[5] = (_Float16)(x1.y * d1.y);
      a[6] = (_Float16)(x1.z * d1.z); a[7] = (_Float16)(x1.w * d1.w);
    } else {
#pragma unroll
      for (int j = 0; j < 8; ++j) a[j] = (_Float16)0.f;
    }
#pragma unroll
    for (int t = 0; t < 16; ++t) {
      half8v b = wfv[(size_t)(ks * 16 + t) * 64 + lane];
      acc[t] = __builtin_amdgcn_mfma_f32_16x16x32_f16(a, b, acc[t], 0, 0, 0);
    }
  }
  int mrow = blockIdx.x * 64 + w * 16 + (lane >> 4) * 4;
  int ncol = lane & 15;
#pragma unroll
  for (int t = 0; t < 16; ++t) {
#pragma unroll
    for (int r = 0; r < 4; ++r) {
      int rr = mrow + r;
      if (rr < NN) Z[(size_t)rr * HH + t * 16 + ncol] = __float2half(acc[t][r]);
    }
  }
}

// ---------------- y fp16 -> fp8 plane ----------------
__global__ __launch_bounds__(256) void k_cvt8(const uint2* __restrict__ y2,
                                              unsigned int* __restrict__ y8) {
  int i = blockIdx.x * 256 + threadIdx.x;  // < NN*64
  uint2 raw = y2[i];
  float2 lo = h2f(raw.x), hi = h2f(raw.y);
  y8[i] = f32x4_to_fp8(lo.x, lo.y, hi.x, hi.y);
}

// ---------------- hop1 all views: gather y8, mask, write interleaved uint4 ----------------
__global__ __launch_bounds__(256) void k_prop1(const unsigned int* __restrict__ y8,
                                               uint4* __restrict__ h8,
                                               const int* __restrict__ rptr,
                                               const int* __restrict__ csort,
                                               const float4* __restrict__ m4) {
  int node = blockIdx.x * 4 + (threadIdx.x >> 6);
  int lane = threadIdx.x & 63;
  int s = rptr[node], e = rptr[node + 1];
  float4 a0, a1, a2, a3;
  {
    float f[4];
    fp8x4_to_f32(y8[(size_t)node * 64 + lane], f);
    float4 m = m4[node];
    a0 = make_float4(f[0] * m.x, f[1] * m.x, f[2] * m.x, f[3] * m.x);
    a1 = make_float4(f[0] * m.y, f[1] * m.y, f[2] * m.y, f[3] * m.y);
    a2 = make_float4(f[0] * m.z, f[1] * m.z, f[2] * m.z, f[3] * m.z);
    a3 = make_float4(f[0] * m.w, f[1] * m.w, f[2] * m.w, f[3] * m.w);
  }
  int j = s;
  for (; j + 1 < e; j += 2) {
    int c0 = csort[j], c1 = csort[j + 1];
    float f0[4], f1[4];
    fp8x4_to_f32(y8[(size_t)c0 * 64 + lane], f0);
    fp8x4_to_f32(y8[(size_t)c1 * 64 + lane], f1);
    float4 p = m4[c0];
    float4 q = m4[c1];
    a0.x += f0[0] * p.x + f1[0] * q.x; a0.y += f0[1] * p.x + f1[1] * q.x;
    a0.z += f0[2] * p.x + f1[2] * q.x; a0.w += f0[3] * p.x + f1[3] * q.x;
    a1.x += f0[0] * p.y + f1[0] * q.y; a1.y += f0[1] * p.y + f1[1] * q.y;
    a1.z += f0[2] * p.y + f1[2] * q.y; a1.w += f0[3] * p.y + f1[3] * q.y;
    a2.x += f0[0] * p.z + f1[0] * q.z; a2.y += f0[1] * p.z + f1[1] * q.z;
    a2.z += f0[2] * p.z + f1[2] * q.z; a2.w += f0[3] * p.z + f1[3] * q.z;
    a3.x += f0[0] * p.w + f1[0] * q.w; a3.y += f0[1] * p.w + f1[1] * q.w;
    a3.z += f0[2] * p.w + f1[2] * q.w; a3.w += f0[3] * p.w + f1[3] * q.w;
  }
  if (j < e) {
    int c0 = csort[j];
    float f0[4];
    fp8x4_to_f32(y8[(size_t)c0 * 64 + lane], f0);
    float4 p = m4[c0];
    a0.x += f0[0] * p.x; a0.y += f0[1] * p.x; a0.z += f0[2] * p.x; a0.w += f0[3] * p.x;
    a1.x += f0[0] * p.y; a1.y += f0[1] * p.y; a1.z += f0[2] * p.y; a1.w += f0[3] * p.y;
    a2.x += f0[0] * p.z; a2.y += f0[1] * p.z; a2.z += f0[2] * p.z; a2.w += f0[3] * p.z;
    a3.x += f0[0] * p.w; a3.y += f0[1] * p.w; a3.z += f0[2] * p.w; a3.w += f0[3] * p.w;
  }
  float sc = 1.0f / (float)(e - s + 1);
  uint4 o;
  o.x = f32x4_to_fp8(a0.x * sc, a0.y * sc, a0.z * sc, a0.w * sc);
  o.y = f32x4_to_fp8(a1.x * sc, a1.y * sc, a1.z * sc, a1.w * sc);
  o.z = f32x4_to_fp8(a2.x * sc, a2.y * sc, a2.z * sc, a2.w * sc);
  o.w = f32x4_to_fp8(a3.x * sc, a3.y * sc, a3.z * sc, a3.w * sc);
  h8[(size_t)node * 64 + lane] = o;
}

// ---------------- hop2 all views: uint4 gather -> uint4 write ----------------
__global__ __launch_bounds__(256) void k_prop2a(const uint4* __restrict__ in,
                                                uint4* __restrict__ out,
                                                const int* __restrict__ rptr,
                                                const int* __restrict__ csort) {
  int node = blockIdx.x * 4 + (threadIdx.x >> 6);
  int lane = threadIdx.x & 63;
  int s = rptr[node], e = rptr[node + 1];
  float4 a0, a1, a2, a3;
  {
    uint4 r = in[(size_t)node * 64 + lane];
    float f0[4], f1[4], f2[4], f3[4];
    fp8x4_to_f32(r.x, f0); fp8x4_to_f32(r.y, f1);
    fp8x4_to_f32(r.z, f2); fp8x4_to_f32(r.w, f3);
    a0 = make_float4(f0[0], f0[1], f0[2], f0[3]);
    a1 = make_float4(f1[0], f1[1], f1[2], f1[3]);
    a2 = make_float4(f2[0], f2[1], f2[2], f2[3]);
    a3 = make_float4(f3[0], f3[1], f3[2], f3[3]);
  }
  int j = s;
  for (; j + 1 < e; j += 2) {
    int c0 = csort[j], c1 = csort[j + 1];
    uint4 r0 = in[(size_t)c0 * 64 + lane];
    uint4 r1 = in[(size_t)c1 * 64 + lane];
    float g0[4], g1[4], g2[4], g3[4], h0[4], h1v[4], h2v[4], h3[4];
    fp8x4_to_f32(r0.x, g0); fp8x4_to_f32(r0.y, g1);
    fp8x4_to_f32(r0.z, g2); fp8x4_to_f32(r0.w, g3);
    fp8x4_to_f32(r1.x, h0); fp8x4_to_f32(r1.y, h1v);
    fp8x4_to_f32(r1.z, h2v); fp8x4_to_f32(r1.w, h3);
    a0.x += g0[0] + h0[0]; a0.y += g0[1] + h0[1]; a0.z += g0[2] + h0[2]; a0.w += g0[3] + h0[3];
    a1.x += g1[0] + h1v[0]; a1.y += g1[1] + h1v[1]; a1.z += g1[2] + h1v[2]; a1.w += g1[3] + h1v[3];
    a2.x += g2[0] + h2v[0]; a2.y += g2[1] + h2v[1]; a2.z += g2[2] + h2v[2]; a2.w += g2[3] + h2v[3];
    a3.x += g3[0] + h3[0]; a3.y += g3[1] + h3[1]; a3.z += g3[2] + h3[2]; a3.w += g3[3] + h3[3];
  }
  if (j < e) {
    int c0 = csort[j];
    uint4 r0 = in[(size_t)c0 * 64 + lane];
    float g0[4], g1[4], g2[4], g3[4];
    fp8x4_to_f32(r0.x, g0); fp8x4_to_f32(r0.y, g1);
    fp8x4_to_f32(r0.z, g2); fp8x4_to_f32(r0.w, g3);
    a0.x += g0[0]; a0.y += g0[1]; a0.z += g0[2]; a0.w += g0[3];
    a1.x += g1[0]; a1.y += g1[1]; a1.z += g1[2]; a1.w += g1[3];
    a2.x += g2[0]; a2.y += g2[1]; a2.z += g2[2]; a2.w += g2[3];
    a3.x += g3[0]; a3.y += g3[1]; a3.z += g3[2]; a3.w += g3[3];
  }
  float sc = 1.0f / (float)(e - s + 1);
  uint4 o;
  o.x = f32x4_to_fp8(a0.x * sc, a0.y * sc, a0.z * sc, a0.w * sc);
  o.y = f32x4_to_fp8(a1.x * sc, a1.y * sc, a1.z * sc, a1.w * sc);
  o.z = f32x4_to_fp8(a2.x * sc, a2.y * sc, a2.z * sc, a2.w * sc);
  o.w = f32x4_to_fp8(a3.x * sc, a3.y * sc, a3.z * sc, a3.w * sc);
  out[(size_t)node * 64 + lane] = o;
}

// ---------------- hop3 all views + bias + relu + pool ----------------
__global__ __launch_bounds__(256) void k_prop3a(const uint4* __restrict__ in,
                                                const int* __restrict__ rptr,
                                                const int* __restrict__ csort,
                                                const int* __restrict__ batch,
                                                const float* __restrict__ b1,
                                                float* __restrict__ part) {
  int w = threadIdx.x >> 6, lane = threadIdx.x & 63;
  int node = blockIdx.x * 4 + w;
  __shared__ float red[4][VV][HH];  // 16 KB
  __shared__ int bb[4];
  int s = rptr[node], e = rptr[node + 1];
  float4 a0, a1, a2, a3;
  {
    uint4 r = in[(size_t)node * 64 + lane];
    float f0[4], f1[4], f2[4], f3[4];
    fp8x4_to_f32(r.x, f0); fp8x4_to_f32(r.y, f1);
    fp8x4_to_f32(r.z, f2); fp8x4_to_f32(r.w, f3);
    a0 = make_float4(f0[0], f0[1], f0[2], f0[3]);
    a1 = make_float4(f1[0], f1[1], f1[2], f1[3]);
    a2 = make_float4(f2[0], f2[1], f2[2], f2[3]);
    a3 = make_float4(f3[0], f3[1], f3[2], f3[3]);
  }
  int j = s;
  for (; j + 1 < e; j += 2) {
    int c0 = csort[j], c1 = csort[j + 1];
    uint4 r0 = in[(size_t)c0 * 64 + lane];
    uint4 r1 = in[(size_t)c1 * 64 + lane];
    float g0[4], g1[4], g2[4], g3[4], h0[4], h1v[4], h2v[4], h3[4];
    fp8x4_to_f32(r0.x, g0); fp8x4_to_f32(r0.y, g1);
    fp8x4_to_f32(r0.z, g2); fp8x4_to_f32(r0.w, g3);
    fp8x4_to_f32(r1.x, h0); fp8x4_to_f32(r1.y, h1v);
    fp8x4_to_f32(r1.z, h2v); fp8x4_to_f32(r1.w, h3);
    a0.x += g0[0] + h0[0]; a0.y += g0[1] + h0[1]; a0.z += g0[2] + h0[2]; a0.w += g0[3] + h0[3];
    a1.x += g1[0] + h1v[0]; a1.y += g1[1] + h1v[1]; a1.z += g1[2] + h1v[2]; a1.w += g1[3] + h1v[3];
    a2.x += g2[0] + h2v[0]; a2.y += g2[1] + h2v[1]; a2.z += g2[2] + h2v[2]; a2.w += g2[3] + h2v[3];
    a3.x += g3[0] + h3[0]; a3.y += g3[1] + h3[1]; a3.z += g3[2] + h3[2]; a3.w += g3[3] + h3[3];
  }
  if (j < e) {
    int c0 = csort[j];
    uint4 r0 = in[(size_t)c0 * 64 + lane];
    float g0[4], g1[4], g2[4], g3[4];
    fp8x4_to_f32(r0.x, g0); fp8x4_to_f32(r0.y, g1);
    fp8x4_to_f32(r0.z, g2); fp8x4_to_f32(r0.w, g3);
    a0.x += g0[0]; a0.y += g0[1]; a0.z += g0[2]; a0.w += g0[3];
    a1.x += g1[0]; a1.y += g1[1]; a1.z += g1[2]; a1.w += g1[3];
    a2.x += g2[0]; a2.y += g2[1]; a2.z += g2[2]; a2.w += g2[3];
    a3.x += g3[0]; a3.y += g3[1]; a3.z += g3[2]; a3.w += g3[3];
  }
  float sc = 1.0f / (float)(e - s + 1);
  float4 bv = *reinterpret_cast<const float4*>(&b1[lane * 4]);
  red[w][0][lane * 4 + 0] = fmaxf(a0.x * sc + bv.x, 0.f);
  red[w][0][lane * 4 + 1] = fmaxf(a0.y * sc + bv.y, 0.f);
  red[w][0][lane * 4 + 2] = fmaxf(a0.z * sc + bv.z, 0.f);
  red[w][0][lane * 4 + 3] = fmaxf(a0.w * sc + bv.w, 0.f);
  red[w][1][lane * 4 + 0] = fmaxf(a1.x * sc + bv.x, 0.f);
  red[w][1][lane * 4 + 1] = fmaxf(a1.y * sc + bv.y, 0.f);
  red[w][1][lane * 4 + 2] = fmaxf(a1.z * sc + bv.z, 0.f);
  red[w][1][lane * 4 + 3] = fmaxf(a1.w * sc + bv.w, 0.f);
  red[w][2][lane * 4 + 0] = fmaxf(a2.x * sc + bv.x, 0.f);
  red[w][2][lane * 4 + 1] = fmaxf(a2.y * sc + bv.y, 0.f);
  red[w][2][lane * 4 + 2] = fmaxf(a2.z * sc + bv.z, 0.f);
  red[w][2][lane * 4 + 3] = fmaxf(a2.w * sc + bv.w, 0.f);
  red[w][3][lane * 4 + 0] = fmaxf(a3.x * sc + bv.x, 0.f);
  red[w][3][lane * 4 + 1] = fmaxf(a3.y * sc + bv.y, 0.f);
  red[w][3][lane * 4 + 2] = fmaxf(a3.z * sc + bv.z, 0.f);
  red[w][3][lane * 4 + 3] = fmaxf(a3.w * sc + bv.w, 0.f);
  if (lane == 0) bb[w] = batch[node];
  __syncthreads();
  int strip = blockIdx.x & (SS - 1);
  if (bb[0] == bb[1] && bb[1] == bb[2] && bb[2] == bb[3]) {
    int col = threadIdx.x;
    int b = bb[0];
#pragma unroll
    for (int v = 0; v < VV; ++v) {
      float sum = red[0][v][col] + red[1][v][col] + red[2][v][col] + red[3][v][col];
      atomicAdd(&part[(((size_t)v * SS + strip) * BB + b) * HH + col], sum);
    }
  } else {
    int b = bb[w];
#pragma unroll
    for (int v = 0; v < VV; ++v)
#pragma unroll
      for (int k = 0; k < 4; ++k)
        atomicAdd(&part[(((size_t)v * SS + strip) * BB + b) * HH + lane * 4 + k],
                  red[w][v][lane * 4 + k]);
  }
}

// ---------------- head: meanpool -> @W2+b2 -> @Wc+bc -> softmax ----------------
__global__ __launch_bounds__(256) void k_head(const float* __restrict__ part,
                                              const int* __restrict__ bptr,
                                              const float* __restrict__ W2,
                                              const float* __restrict__ b2,
                                              const float* __restrict__ Wc,
                                              const float* __restrict__ bc,
                                              float* __restrict__ probs,
                                              float* __restrict__ logits) {
  int v = blockIdx.x / BB;
  int b = blockIdx.x % BB;
  int h = threadIdx.x;
  __shared__ float mr[HH];
  __shared__ float vr[HH];
  __shared__ float scs[CC];
  float acc = 0.f;
  for (int s = 0; s < SS; ++s)
    acc += part[(((size_t)v * SS + s) * BB + b) * HH + h];
  int cnt = bptr[b + 1] - bptr[b]; if (cnt < 1) cnt = 1;
  mr[h] = acc / (float)cnt;
  __syncthreads();
  float a = b2[h];
  for (int k = 0; k < HH; ++k) a += mr[k] * W2[k * HH + h];
  vr[h] = a;
  __syncthreads();
  if (h < CC) {
    float t = bc[h];
    for (int k = 0; k < HH; ++k) t += vr[k] * Wc[k * CC + h];
    scs[h] = t;
  }
  __syncthreads();
  if (h < CC) {
    float m = scs[0];
    for (int c = 1; c < CC; ++c) m = fmaxf(m, scs[c]);
    float den = 0.f;
    for (int c = 0; c < CC; ++c) den += expf(scs[c] - m);
    float p = expf(scs[h] - m) / den;
    probs[((size_t)v * BB + b) * CC + h] = p;
    if (v == 0) logits[b * CC + h] = scs[h];
  }
}

// ---------------- loss: consistency + entropy ----------------
__global__ __launch_bounds__(256) void k_loss(const float* __restrict__ probs, float* __restrict__ out) {
  __shared__ float mp[BB * CC];
  __shared__ float red[8];
  int tid = threadIdx.x;
  float ent = 0.f;
  for (int i = tid; i < BB * CC; i += 256) {
    float m = 0.25f * (probs[i] + probs[BB * CC + i] + probs[2 * BB * CC + i] + probs[3 * BB * CC + i]);
    mp[i] = m;
    ent += m * logf(m + 1e-8f);
  }
  __syncthreads();
  float cons = 0.f;
  for (int i = tid; i < VV * BB * CC; i += 256) {
    float d = probs[i] - mp[i % (BB * CC)];
    cons += d * d;
  }
  for (int o = 32; o > 0; o >>= 1) {
    cons += __shfl_down(cons, o, 64);
    ent += __shfl_down(ent, o, 64);
  }
  int wid = tid >> 6, lane = tid & 63;
  if (lane == 0) { red[wid] = cons; red[4 + wid] = ent; }
  __syncthreads();
  if (tid == 0) {
    float c = red[0] + red[1] + red[2] + red[3];
    float e2 = red[4] + red[5] + red[6] + red[7];
    out[0] = c / (float)(VV * BB) - e2 / (float)BB;
  }
}

extern "C" void kernel_launch(void* const* d_in, const int* in_sizes, int n_in,
                              void* d_out, int out_size, void* d_ws, size_t ws_size,
                              hipStream_t stream) {
  const float* x     = (const float*)d_in[0];
  const int*   erow  = (const int*)d_in[1];          // edge_index[0]
  const int*   ecol  = ((const int*)d_in[1]) + EE;   // edge_index[1]
  const int*   batch = (const int*)d_in[2];
  const float* dm    = (const float*)d_in[3];
  const float* nmask = (const float*)d_in[4];
  const float* W1    = (const float*)d_in[5];
  const float* b1    = (const float*)d_in[6];
  const float* W2    = (const float*)d_in[7];
  const float* b2    = (const float*)d_in[8];
  const float* Wc    = (const float*)d_in[9];
  const float* bc    = (const float*)d_in[10];
  float* out = (float*)d_out;

  char* ws = (char*)d_ws;
  size_t off = 0;
  auto carve = [&](size_t bytes) -> char* {
    char* p = ws + off;
    off = (off + bytes + 255) & ~(size_t)255;
    return p;
  };
  float* part  = (float*)carve((size_t)VV * SS * BB * HH * 4);
  int*   deg   = (int*)carve((size_t)NN * 4);
  int*   fill  = (int*)carve((size_t)NN * 4);
  int*   rptr  = (int*)carve((size_t)(NN + 1) * 4);
  int*   csort = (int*)carve((size_t)EE * 4);
  int*   bptr  = (int*)carve((size_t)(BB + 1) * 4);
  int*   bsum  = (int*)carve(256 * 4);
  int*   boff  = (int*)carve(256 * 4);
  float* probs = (float*)carve((size_t)VV * BB * CC * 4);
  float4* m4   = (float4*)carve((size_t)NN * 16);
  _Float16* wf = (_Float16*)carve((size_t)8 * 16 * 64 * 8 * 2);  // 128 KB

  const size_t NFh = (size_t)NN * FF * 2;  // 25.6 MB fp16 node-feature plane
  __half* y  = (__half*)carve(NFh);                           // GEMM out (fp16)
  unsigned int* y8 = (unsigned int*)carve((size_t)NN * 256);  // 12.8 MB fp8 plane
  uint4* h8  = (uint4*)carve((size_t)NN * 64 * 16);           // 51.2 MB interleaved 4-view fp8
  uint4* h8b = (uint4*)carve((size_t)NN * 64 * 16);           // 51.2 MB

  hipMemsetAsync(deg, 0, (size_t)NN * 4, stream);
  hipMemsetAsync(fill, 0, (size_t)NN * 4, stream);
  hipMemsetAsync(part, 0, (size_t)VV * SS * BB * HH * 4, stream);

  k_deg<<<(EE + 255) / 256, 256, 0, stream>>>(erow, deg);
  k_scan1<<<NBLK, 256, 0, stream>>>(deg, bsum);
  k_scan2<<<1, 256, 0, stream>>>(bsum, boff);
  k_scan3<<<NBLK, 256, 0, stream>>>(deg, boff, rptr);
  k_scatter<<<(EE + 255) / 256, 256, 0, stream>>>(erow, ecol, rptr, fill, csort);
  k_bptr<<<1, 256, 0, stream>>>(batch, bptr);
  k_packm<<<(NN + 255) / 256, 256, 0, stream>>>(nmask, m4);
  k_wfrag<<<32, 256, 0, stream>>>(W1, wf);

  k_gemm<<<(NN + 63) / 64, 256, 0, stream>>>(x, dm, wf, y);
  k_cvt8<<<(NN * 64) / 256, 256, 0, stream>>>((const uint2*)y, y8);
  k_prop1<<<NN / 4, 256, 0, stream>>>(y8, h8, rptr, csort, m4);
  k_prop2a<<<NN / 4, 256, 0, stream>>>(h8, h8b, rptr, csort);
  k_prop3a<<<NN / 4, 256, 0, stream>>>(h8b, rptr, csort, batch, b1, part);
  k_head<<<VV * BB, 256, 0, stream>>>(part, bptr, W2, b2, Wc, bc, probs, out);
  k_loss<<<1, 256, 0, stream>>>(probs, out + BB * CC);
}